// Round 5
// baseline (411.526 us; speedup 1.0000x reference)
//
#include <hip/hip_runtime.h>
#include <stdint.h>

#define T_FRAMES 32
#define NNODES 10000
#define NEDGES 160000
#define HID 128

typedef short v8s __attribute__((ext_vector_type(8)));
typedef float v4f __attribute__((ext_vector_type(4)));

static __device__ __forceinline__ ushort f2bf(float f){
  uint32_t u = __float_as_uint(f);
  u += 0x7FFFu + ((u >> 16) & 1u);
  return (ushort)(u >> 16);
}
static __device__ __forceinline__ float bf_lo(uint32_t u){
  return __uint_as_float(u << 16);
}
static __device__ __forceinline__ float bf_hi(uint32_t u){
  return __uint_as_float(u & 0xffff0000u);
}
// fast native transcendentals (v_exp_f32 + v_rcp_f32)
static __device__ __forceinline__ float fsigm(float x){
  return __fdividef(1.0f, 1.0f + __expf(-x));
}
static __device__ __forceinline__ float fsilu(float x){
  return x * fsigm(x);
}
static __device__ __forceinline__ float ftanh(float x){
  return 2.0f * fsigm(2.0f * x) - 1.0f;
}

// ---------------- degree / norms / CSR build ----------------

__global__ void k_degree(const int* __restrict__ src, const int* __restrict__ dst,
                         int* cnt_out, int* cnt_in, int E){
  int e = blockIdx.x*blockDim.x + threadIdx.x;
  if (e < E){
    atomicAdd(&cnt_out[src[e]], 1);
    atomicAdd(&cnt_in[dst[e]], 1);
  }
}

__global__ void k_norms(const int* __restrict__ cnt_out, const int* __restrict__ cnt_in,
                        float* norm_out, float* norm_in, int N){
  int n = blockIdx.x*blockDim.x + threadIdx.x;
  if (n < N){
    norm_out[n] = rsqrtf((float)max(cnt_out[n], 1));
    norm_in[n]  = rsqrtf((float)max(cnt_in[n], 1));
  }
}

__global__ void __launch_bounds__(1024) k_scan(const int* __restrict__ cnt_in,
                                               int* row_ptr, int* cursor, int N){
  __shared__ int sm[1024];
  __shared__ int carry_s;
  if (threadIdx.x == 0) carry_s = 0;
  __syncthreads();
  for (int base = 0; base < N; base += 1024){
    int i = base + threadIdx.x;
    int v = (i < N) ? cnt_in[i] : 0;
    sm[threadIdx.x] = v;
    __syncthreads();
    for (int off = 1; off < 1024; off <<= 1){
      int tv = (threadIdx.x >= off) ? sm[threadIdx.x - off] : 0;
      __syncthreads();
      sm[threadIdx.x] += tv;
      __syncthreads();
    }
    int excl = sm[threadIdx.x] - v;
    if (i < N){ row_ptr[i] = carry_s + excl; cursor[i] = carry_s + excl; }
    __syncthreads();
    if (threadIdx.x == 0) carry_s += sm[1023];
    __syncthreads();
  }
  if (threadIdx.x == 0) row_ptr[N] = carry_s;
}

__global__ void k_fill(const int* __restrict__ src, const int* __restrict__ dst,
                       int* cursor, int* es, int E){
  int e = blockIdx.x*blockDim.x + threadIdx.x;
  if (e < E){
    int p = atomicAdd(&cursor[dst[e]], 1);
    es[p] = src[e];
  }
}

// ---------------- transpose features -> node-major, pre-scaled by norm_out ----------------

__global__ void __launch_bounds__(256) k_fnT(const float* __restrict__ feat,
                                             const float* __restrict__ norm_o,
                                             float* __restrict__ fnT, int N){
  __shared__ float sm[32][65];
  int n0 = blockIdx.x*64;
  int tid = threadIdx.x;
  for (int idx = tid; idx < 2048; idx += 256){
    int t = idx >> 6, i = idx & 63;
    int n = n0 + i;
    sm[t][i] = (n < N) ? feat[(size_t)t*N + n] : 0.f;
  }
  __syncthreads();
  for (int idx = tid; idx < 2048; idx += 256){
    int i = idx >> 5, t = idx & 31;
    int n = n0 + i;
    if (n < N) fnT[(size_t)n*32 + t] = sm[t][i] * norm_o[n];
  }
}

// ---------------- gconv1 (node-major): one wave per node ----------------

__global__ void __launch_bounds__(256) k_gconv1_nm(
    const float* __restrict__ fnT, const int* __restrict__ row_ptr,
    const int* __restrict__ es, const float* __restrict__ norm_in,
    const float* __restrict__ norm_out,
    const float* __restrict__ W1, const float* __restrict__ b1,
    ushort* __restrict__ h1s, int N){
  __shared__ float w1s[32], b1s[32];
  int tid = threadIdx.x;
  if (tid < 32){ w1s[tid] = W1[tid]; b1s[tid] = b1[tid]; }
  __syncthreads();
  int n = blockIdx.x*4 + (tid >> 6);          // N % 4 == 0
  int lane = tid & 63;
  int ep = lane >> 5, t = lane & 31;
  int s = row_ptr[n], d = row_ptr[n+1];
  float acc = 0.f;
  for (int e = s + ep; e < d; e += 2)
    acc += fnT[(size_t)es[e]*32 + t];
  acc += __shfl_xor(acc, 32);
  float x1 = acc * norm_in[n];
  float x1p = __shfl(x1, lane >> 1);          // lane l gets x1[t = l>>1]
  float no = norm_out[n];
  int j0 = (lane & 1) * 16;
  uint w[8];
  #pragma unroll
  for (int q = 0; q < 8; ++q){
    float h0 = fsilu(fmaf(x1p, w1s[j0+2*q],   b1s[j0+2*q]))   * no;
    float h1 = fsilu(fmaf(x1p, w1s[j0+2*q+1], b1s[j0+2*q+1])) * no;
    w[q] = (uint)f2bf(h0) | ((uint)f2bf(h1) << 16);
  }
  uint4* dp = (uint4*)(h1s + (size_t)n*1024 + lane*16);
  dp[0] = make_uint4(w[0], w[1], w[2], w[3]);
  dp[1] = make_uint4(w[4], w[5], w[6], w[7]);
}

// ---------------- gconv2 (node-major): one wave per node ----------------

__global__ void __launch_bounds__(256) k_gconv2_nm(
    const ushort* __restrict__ h1s, const int* __restrict__ row_ptr,
    const int* __restrict__ es, const float* __restrict__ norm_in,
    ushort* __restrict__ x2, int N){
  int tid = threadIdx.x;
  int n = blockIdx.x*4 + (tid >> 6);
  int lane = tid & 63;
  int s = row_ptr[n], d = row_ptr[n+1];
  float acc[16];
  #pragma unroll
  for (int i = 0; i < 16; ++i) acc[i] = 0.f;

  #define ACC_U4(v, base) do { \
    acc[(base)+0] += bf_lo((v).x); acc[(base)+1] += bf_hi((v).x); \
    acc[(base)+2] += bf_lo((v).y); acc[(base)+3] += bf_hi((v).y); \
    acc[(base)+4] += bf_lo((v).z); acc[(base)+5] += bf_hi((v).z); \
    acc[(base)+6] += bf_lo((v).w); acc[(base)+7] += bf_hi((v).w); \
  } while(0)

  int e = s;
  for (; e + 1 < d; e += 2){
    const uint4* p0 = (const uint4*)(h1s + (size_t)es[e]  *1024) + lane*2;
    const uint4* p1 = (const uint4*)(h1s + (size_t)es[e+1]*1024) + lane*2;
    uint4 a0 = p0[0], a1 = p0[1];
    uint4 c0 = p1[0], c1 = p1[1];
    ACC_U4(a0, 0); ACC_U4(a1, 8);
    ACC_U4(c0, 0); ACC_U4(c1, 8);
  }
  if (e < d){
    const uint4* p0 = (const uint4*)(h1s + (size_t)es[e]*1024) + lane*2;
    uint4 a0 = p0[0], a1 = p0[1];
    ACC_U4(a0, 0); ACC_U4(a1, 8);
  }
  #undef ACC_U4

  float ni = norm_in[n];
  uint w[8];
  #pragma unroll
  for (int q = 0; q < 8; ++q)
    w[q] = (uint)f2bf(acc[2*q]*ni) | ((uint)f2bf(acc[2*q+1]*ni) << 16);
  uint4* dp = (uint4*)(x2 + (size_t)n*1024 + lane*16);
  dp[0] = make_uint4(w[0], w[1], w[2], w[3]);
  dp[1] = make_uint4(w[4], w[5], w[6], w[7]);
}

// ---------------- W2 -> bf16 MFMA B-fragments ----------------

__global__ void k_w2frag(const float* __restrict__ W2, ushort* __restrict__ W2F){
  int tid = blockIdx.x*blockDim.x + threadIdx.x;  // 0..4095
  int j = tid & 7, l = (tid >> 3) & 63, i = tid >> 9;
  int g = l >> 4, n = l & 15;
  W2F[tid] = f2bf(W2[(g*8 + j)*128 + i*16 + n]);
}

// ---------------- linear 32->128 + silu via MFMA (x2 node-major) ----------------
// PHASE 0: gates[t][n] = silu(x2@W2+b2).gate_w + gate_b ; Z[t] += sum exp(gate)
// PHASE 1: pooled[t][:] += (exp(gate)/Z[t]) * silu(x2@W2+b2)

template<int PHASE>
__global__ void __launch_bounds__(256) k_linear_mfma(
    const ushort* __restrict__ x2, const ushort* __restrict__ W2F,
    const float* __restrict__ b2, const float* __restrict__ gate_w,
    const float* __restrict__ gate_b,
    float* __restrict__ gates, float* __restrict__ Z,
    float* __restrict__ pooled, int N){
  __shared__ float pool_s[128];
  int t = blockIdx.y;
  int tid = threadIdx.x;
  int wave = tid >> 6, lane = tid & 63;
  int g = lane >> 4, n = lane & 15;
  if (PHASE == 1){
    if (tid < 128) pool_s[tid] = 0.f;
    __syncthreads();
  }
  int tile = blockIdx.x*4 + wave;          // 16-node tile; N = 625*16
  bool active = (tile*16 < N);

  const v8s* W2Fv = (const v8s*)W2F;
  v8s bfrag[8];
  #pragma unroll
  for (int i = 0; i < 8; ++i) bfrag[i] = W2Fv[i*64 + lane];
  v4f acc[8];
  #pragma unroll
  for (int i = 0; i < 8; ++i){
    float bv = b2[i*16 + n];
    acc[i] = (v4f){bv, bv, bv, bv};
  }
  if (active){
    int nb = tile*16;
    const v8s* ap = (const v8s*)(x2 + (size_t)(nb + (lane & 15))*1024 + t*32);
    v8s a = ap[g];
    #pragma unroll
    for (int i = 0; i < 8; ++i)
      acc[i] = __builtin_amdgcn_mfma_f32_16x16x32_bf16(a, bfrag[i], acc[i], 0, 0, 0);
  }
  // C/D layout: value (i,r) = h[node nb + g*4 + r][col i*16 + n]
  if (PHASE == 0){
    if (active){
      float gw8[8];
      #pragma unroll
      for (int i = 0; i < 8; ++i) gw8[i] = gate_w[i*16 + n];
      float gp[4] = {0.f, 0.f, 0.f, 0.f};
      #pragma unroll
      for (int i = 0; i < 8; ++i){
        #pragma unroll
        for (int r = 0; r < 4; ++r) gp[r] += fsilu(acc[i][r]) * gw8[i];
      }
      #pragma unroll
      for (int m = 1; m < 16; m <<= 1){
        #pragma unroll
        for (int r = 0; r < 4; ++r) gp[r] += __shfl_xor(gp[r], m);
      }
      if (n == 0){
        int nb = tile*16;
        float gb = gate_b[0];
        float se = 0.f;
        #pragma unroll
        for (int r = 0; r < 4; ++r){
          float gv = gp[r] + gb;
          gates[(size_t)t*N + nb + g*4 + r] = gv;
          se += __expf(gv);
        }
        se += __shfl_xor(se, 16);
        se += __shfl_xor(se, 32);
        if (lane == 0) atomicAdd(&Z[t], se);
      }
    }
  } else {
    if (active){
      int nb = tile*16;
      float invZ = __fdividef(1.0f, Z[t]);
      float wn[4];
      #pragma unroll
      for (int r = 0; r < 4; ++r)
        wn[r] = __expf(gates[(size_t)t*N + nb + g*4 + r]) * invZ;
      float cs[8];
      #pragma unroll
      for (int i = 0; i < 8; ++i){
        float c = 0.f;
        #pragma unroll
        for (int r = 0; r < 4; ++r) c += fsilu(acc[i][r]) * wn[r];
        c += __shfl_xor(c, 16);
        c += __shfl_xor(c, 32);
        cs[i] = c;
      }
      if (lane < 16){
        #pragma unroll
        for (int i = 0; i < 8; ++i) atomicAdd(&pool_s[i*16 + lane], cs[i]);
      }
    }
    __syncthreads();
    if (tid < 128) atomicAdd(&pooled[(size_t)t*HID + tid], pool_s[tid]);
  }
}

// ---------------- GRU + head ----------------
// gi[t][o] = pooled[t] . W_ih[o][:] + b_ih[o]   (rows read directly, no transpose)

__global__ void __launch_bounds__(384) k_gi(const float* __restrict__ pooled,
                                            const float* __restrict__ W_ih,
                                            const float* __restrict__ b_ih,
                                            float* __restrict__ gi_all){
  __shared__ float ps[HID];
  int t = blockIdx.x, tid = threadIdx.x;   // 384 threads
  if (tid < HID) ps[tid] = pooled[(size_t)t*HID + tid];
  __syncthreads();
  float acc = b_ih[tid];
  const float4* wr = (const float4*)(W_ih + (size_t)tid*HID);
  const float4* p4 = (const float4*)ps;
  #pragma unroll
  for (int q = 0; q < HID/4; ++q){
    float4 wv = wr[q], pv = p4[q];
    acc = fmaf(wv.x, pv.x, acc);
    acc = fmaf(wv.y, pv.y, acc);
    acc = fmaf(wv.z, pv.z, acc);
    acc = fmaf(wv.w, pv.w, acc);
  }
  gi_all[t*384 + tid] = acc;
}

// weights in named float4 registers; gi staged in LDS; h broadcast via LDS.
__global__ void __launch_bounds__(384, 1) k_gru(
    const float* __restrict__ gi_all, const float* __restrict__ W_hh,
    const float* __restrict__ b_hh,
    const float* __restrict__ d1_w, const float* __restrict__ d1_b,
    const float* __restrict__ d2_w, const float* __restrict__ d2_b,
    float* __restrict__ out){
  __shared__ float gi_s[T_FRAMES*3*HID];   // 48 KB
  __shared__ float h_s[HID];
  __shared__ float gh_s[3*HID];
  __shared__ float o1[16];
  int tid = threadIdx.x;  // 384

  for (int i = tid; i < T_FRAMES*3*HID; i += 384) gi_s[i] = gi_all[i];

  const float4* wr = (const float4*)(W_hh + (size_t)tid*HID);  // row o=tid
  #define LDW(i) float4 W##i = wr[i];
  LDW(0) LDW(1) LDW(2) LDW(3) LDW(4) LDW(5) LDW(6) LDW(7)
  LDW(8) LDW(9) LDW(10) LDW(11) LDW(12) LDW(13) LDW(14) LDW(15)
  LDW(16) LDW(17) LDW(18) LDW(19) LDW(20) LDW(21) LDW(22) LDW(23)
  LDW(24) LDW(25) LDW(26) LDW(27) LDW(28) LDW(29) LDW(30) LDW(31)
  #undef LDW
  float bh = b_hh[tid];

  if (tid < HID) h_s[tid] = 0.f;
  __syncthreads();

  for (int t = 0; t < T_FRAMES; ++t){
    const float4* p4 = (const float4*)h_s;
    float acc = bh;
    #define STEP(i) { float4 pv = p4[i]; \
      acc = fmaf(W##i.x, pv.x, acc); acc = fmaf(W##i.y, pv.y, acc); \
      acc = fmaf(W##i.z, pv.z, acc); acc = fmaf(W##i.w, pv.w, acc); }
    STEP(0) STEP(1) STEP(2) STEP(3) STEP(4) STEP(5) STEP(6) STEP(7)
    STEP(8) STEP(9) STEP(10) STEP(11) STEP(12) STEP(13) STEP(14) STEP(15)
    STEP(16) STEP(17) STEP(18) STEP(19) STEP(20) STEP(21) STEP(22) STEP(23)
    STEP(24) STEP(25) STEP(26) STEP(27) STEP(28) STEP(29) STEP(30) STEP(31)
    #undef STEP
    gh_s[tid] = acc;
    __syncthreads();
    if (tid < HID){
      const float* gi = gi_s + t*384;
      float r  = fsigm(gi[tid]       + gh_s[tid]);
      float z  = fsigm(gi[HID+tid]   + gh_s[HID+tid]);
      float nn = ftanh(gi[2*HID+tid] + r*gh_s[2*HID+tid]);
      h_s[tid] = (1.f - z)*nn + z*h_s[tid];
    }
    __syncthreads();
  }
  if (tid < 16){
    float acc = d1_b[tid];
    #pragma unroll 4
    for (int j = 0; j < HID; ++j) acc = fmaf(h_s[j], d1_w[j*16 + tid], acc);
    o1[tid] = fsilu(acc);
  }
  __syncthreads();
  if (tid < 4){
    float acc = d2_b[tid];
    #pragma unroll
    for (int j = 0; j < 16; ++j) acc = fmaf(o1[j], d2_w[j*4 + tid], acc);
    out[tid] = fsigm(fsilu(acc));
  }
}

// ---------------- launch ----------------

extern "C" void kernel_launch(void* const* d_in, const int* in_sizes, int n_in,
                              void* d_out, int out_size, void* d_ws, size_t ws_size,
                              hipStream_t stream){
  const float* features = (const float*)d_in[0];
  const int*   src      = (const int*)  d_in[1];
  const int*   dst      = (const int*)  d_in[2];
  const float* W1       = (const float*)d_in[3];
  const float* b1       = (const float*)d_in[4];
  const float* W2       = (const float*)d_in[5];
  const float* b2       = (const float*)d_in[6];
  const float* gate_w   = (const float*)d_in[7];
  const float* gate_b   = (const float*)d_in[8];
  const float* W_ih     = (const float*)d_in[9];
  const float* W_hh     = (const float*)d_in[10];
  const float* b_ih     = (const float*)d_in[11];
  const float* b_hh     = (const float*)d_in[12];
  const float* d1_w     = (const float*)d_in[13];
  const float* d1_b     = (const float*)d_in[14];
  const float* d2_w     = (const float*)d_in[15];
  const float* d2_b     = (const float*)d_in[16];
  float* out = (float*)d_out;

  const int N = NNODES, E = NEDGES, T = T_FRAMES;

  char* base = (char*)d_ws;
  size_t off = 0;
  auto alloc = [&](size_t bytes)->void*{
    void* p = base + off;
    off = (off + bytes + 255) & ~(size_t)255;
    return p;
  };
  int*    cnt_out = (int*)   alloc((size_t)N*4);
  int*    cnt_in  = (int*)   alloc((size_t)N*4);
  int*    row_ptr = (int*)   alloc((size_t)(N+1)*4);
  int*    cursor  = (int*)   alloc((size_t)N*4);
  float*  norm_o  = (float*) alloc((size_t)N*4);
  float*  norm_i  = (float*) alloc((size_t)N*4);
  int*    es      = (int*)   alloc((size_t)E*4);
  float*  fnT     = (float*) alloc((size_t)N*T*4);
  ushort* h1s     = (ushort*)alloc((size_t)N*T*32*2);
  ushort* x2      = (ushort*)alloc((size_t)N*T*32*2);
  float*  gates   = (float*) alloc((size_t)T*N*4);
  float*  Z       = (float*) alloc((size_t)T*4);
  float*  pooled  = (float*) alloc((size_t)T*HID*4);
  float*  gi_all  = (float*) alloc((size_t)T*3*HID*4);
  ushort* W2F     = (ushort*)alloc((size_t)8*64*8*2);
  (void)ws_size; (void)in_sizes; (void)n_in; (void)out_size;

  hipMemsetAsync(cnt_out, 0, (size_t)N*4, stream);
  hipMemsetAsync(cnt_in,  0, (size_t)N*4, stream);
  hipMemsetAsync(pooled,  0, (size_t)T*HID*4, stream);
  hipMemsetAsync(Z,       0, (size_t)T*4, stream);

  k_degree<<<(E+255)/256, 256, 0, stream>>>(src, dst, cnt_out, cnt_in, E);
  k_norms <<<(N+255)/256, 256, 0, stream>>>(cnt_out, cnt_in, norm_o, norm_i, N);
  k_scan  <<<1, 1024, 0, stream>>>(cnt_in, row_ptr, cursor, N);
  k_fill  <<<(E+255)/256, 256, 0, stream>>>(src, dst, cursor, es, E);

  k_fnT      <<<(N+63)/64, 256, 0, stream>>>(features, norm_o, fnT, N);
  k_gconv1_nm<<<N/4, 256, 0, stream>>>(fnT, row_ptr, es, norm_i, norm_o, W1, b1, h1s, N);
  k_gconv2_nm<<<N/4, 256, 0, stream>>>(h1s, row_ptr, es, norm_i, x2, N);

  k_w2frag<<<16, 256, 0, stream>>>(W2, W2F);

  const int NT = (N + 15) / 16;           // 625 16-node tiles
  const int GX = (NT + 3) / 4;            // 4 waves (tiles) per block
  k_linear_mfma<0><<<dim3(GX, T), 256, 0, stream>>>(x2, W2F, b2, gate_w, gate_b, gates, Z, pooled, N);
  k_linear_mfma<1><<<dim3(GX, T), 256, 0, stream>>>(x2, W2F, b2, gate_w, gate_b, gates, Z, pooled, N);

  k_gi <<<T, 384, 0, stream>>>(pooled, W_ih, b_ih, gi_all);
  k_gru<<<1, 384, 0, stream>>>(gi_all, W_hh, b_hh, d1_w, d1_b, d2_w, d2_b, out);
}

// Round 6
// 241.669 us; speedup vs baseline: 1.7028x; 1.7028x over previous
//
#include <hip/hip_runtime.h>
#include <stdint.h>

#define T_FRAMES 32
#define NNODES 10000
#define NEDGES 160000
#define HID 128
#define GXL 157   // ceil(625 tiles / 4 waves)

typedef short v8s __attribute__((ext_vector_type(8)));
typedef float v4f __attribute__((ext_vector_type(4)));

static __device__ __forceinline__ ushort f2bf(float f){
  uint32_t u = __float_as_uint(f);
  u += 0x7FFFu + ((u >> 16) & 1u);
  return (ushort)(u >> 16);
}
static __device__ __forceinline__ float bf_lo(uint32_t u){
  return __uint_as_float(u << 16);
}
static __device__ __forceinline__ float bf_hi(uint32_t u){
  return __uint_as_float(u & 0xffff0000u);
}
// fast native transcendentals (v_exp_f32 + v_rcp_f32)
static __device__ __forceinline__ float fsigm(float x){
  return __fdividef(1.0f, 1.0f + __expf(-x));
}
static __device__ __forceinline__ float fsilu(float x){
  return x * fsigm(x);
}
static __device__ __forceinline__ float ftanh(float x){
  return 2.0f * fsigm(2.0f * x) - 1.0f;
}

// ---------------- degree / norms / CSR build ----------------

__global__ void k_degree(const int* __restrict__ src, const int* __restrict__ dst,
                         int* cnt_out, int* cnt_in, int E){
  int e = blockIdx.x*blockDim.x + threadIdx.x;
  if (e < E){
    atomicAdd(&cnt_out[src[e]], 1);
    atomicAdd(&cnt_in[dst[e]], 1);
  }
}

__global__ void k_norms(const int* __restrict__ cnt_out, const int* __restrict__ cnt_in,
                        float* norm_out, float* norm_in, int N){
  int n = blockIdx.x*blockDim.x + threadIdx.x;
  if (n < N){
    norm_out[n] = rsqrtf((float)max(cnt_out[n], 1));
    norm_in[n]  = rsqrtf((float)max(cnt_in[n], 1));
  }
}

__global__ void __launch_bounds__(1024) k_scan(const int* __restrict__ cnt_in,
                                               int* row_ptr, int* cursor, int N){
  __shared__ int sm[1024];
  __shared__ int carry_s;
  if (threadIdx.x == 0) carry_s = 0;
  __syncthreads();
  for (int base = 0; base < N; base += 1024){
    int i = base + threadIdx.x;
    int v = (i < N) ? cnt_in[i] : 0;
    sm[threadIdx.x] = v;
    __syncthreads();
    for (int off = 1; off < 1024; off <<= 1){
      int tv = (threadIdx.x >= off) ? sm[threadIdx.x - off] : 0;
      __syncthreads();
      sm[threadIdx.x] += tv;
      __syncthreads();
    }
    int excl = sm[threadIdx.x] - v;
    if (i < N){ row_ptr[i] = carry_s + excl; cursor[i] = carry_s + excl; }
    __syncthreads();
    if (threadIdx.x == 0) carry_s += sm[1023];
    __syncthreads();
  }
  if (threadIdx.x == 0) row_ptr[N] = carry_s;
}

__global__ void k_fill(const int* __restrict__ src, const int* __restrict__ dst,
                       int* cursor, int* es, int E){
  int e = blockIdx.x*blockDim.x + threadIdx.x;
  if (e < E){
    int p = atomicAdd(&cursor[dst[e]], 1);
    es[p] = src[e];
  }
}

// ---------------- transpose features -> node-major, pre-scaled by norm_out ----------------

__global__ void __launch_bounds__(256) k_fnT(const float* __restrict__ feat,
                                             const float* __restrict__ norm_o,
                                             float* __restrict__ fnT, int N){
  __shared__ float sm[32][65];
  int n0 = blockIdx.x*64;
  int tid = threadIdx.x;
  for (int idx = tid; idx < 2048; idx += 256){
    int t = idx >> 6, i = idx & 63;
    int n = n0 + i;
    sm[t][i] = (n < N) ? feat[(size_t)t*N + n] : 0.f;
  }
  __syncthreads();
  for (int idx = tid; idx < 2048; idx += 256){
    int i = idx >> 5, t = idx & 31;
    int n = n0 + i;
    if (n < N) fnT[(size_t)n*32 + t] = sm[t][i] * norm_o[n];
  }
}

// ---------------- gconv1 (node-major): one wave per node ----------------

__global__ void __launch_bounds__(256) k_gconv1_nm(
    const float* __restrict__ fnT, const int* __restrict__ row_ptr,
    const int* __restrict__ es, const float* __restrict__ norm_in,
    const float* __restrict__ norm_out,
    const float* __restrict__ W1, const float* __restrict__ b1,
    ushort* __restrict__ h1s, int N){
  __shared__ float w1s[32], b1s[32];
  int tid = threadIdx.x;
  if (tid < 32){ w1s[tid] = W1[tid]; b1s[tid] = b1[tid]; }
  __syncthreads();
  int n = blockIdx.x*4 + (tid >> 6);          // N % 4 == 0
  int lane = tid & 63;
  int ep = lane >> 5, t = lane & 31;
  int s = row_ptr[n], d = row_ptr[n+1];
  float acc = 0.f;
  for (int e = s + ep; e < d; e += 2)
    acc += fnT[(size_t)es[e]*32 + t];
  acc += __shfl_xor(acc, 32);
  float x1 = acc * norm_in[n];
  float x1p = __shfl(x1, lane >> 1);          // lane l gets x1[t = l>>1]
  float no = norm_out[n];
  int j0 = (lane & 1) * 16;
  uint w[8];
  #pragma unroll
  for (int q = 0; q < 8; ++q){
    float h0 = fsilu(fmaf(x1p, w1s[j0+2*q],   b1s[j0+2*q]))   * no;
    float h1 = fsilu(fmaf(x1p, w1s[j0+2*q+1], b1s[j0+2*q+1])) * no;
    w[q] = (uint)f2bf(h0) | ((uint)f2bf(h1) << 16);
  }
  uint4* dp = (uint4*)(h1s + (size_t)n*1024 + lane*16);
  dp[0] = make_uint4(w[0], w[1], w[2], w[3]);
  dp[1] = make_uint4(w[4], w[5], w[6], w[7]);
}

// ---------------- gconv2 (node-major): one wave per node ----------------

__global__ void __launch_bounds__(256) k_gconv2_nm(
    const ushort* __restrict__ h1s, const int* __restrict__ row_ptr,
    const int* __restrict__ es, const float* __restrict__ norm_in,
    ushort* __restrict__ x2, int N){
  int tid = threadIdx.x;
  int n = blockIdx.x*4 + (tid >> 6);
  int lane = tid & 63;
  int s = row_ptr[n], d = row_ptr[n+1];
  float acc[16];
  #pragma unroll
  for (int i = 0; i < 16; ++i) acc[i] = 0.f;

  #define ACC_U4(v, base) do { \
    acc[(base)+0] += bf_lo((v).x); acc[(base)+1] += bf_hi((v).x); \
    acc[(base)+2] += bf_lo((v).y); acc[(base)+3] += bf_hi((v).y); \
    acc[(base)+4] += bf_lo((v).z); acc[(base)+5] += bf_hi((v).z); \
    acc[(base)+6] += bf_lo((v).w); acc[(base)+7] += bf_hi((v).w); \
  } while(0)

  int e = s;
  for (; e + 1 < d; e += 2){
    const uint4* p0 = (const uint4*)(h1s + (size_t)es[e]  *1024) + lane*2;
    const uint4* p1 = (const uint4*)(h1s + (size_t)es[e+1]*1024) + lane*2;
    uint4 a0 = p0[0], a1 = p0[1];
    uint4 c0 = p1[0], c1 = p1[1];
    ACC_U4(a0, 0); ACC_U4(a1, 8);
    ACC_U4(c0, 0); ACC_U4(c1, 8);
  }
  if (e < d){
    const uint4* p0 = (const uint4*)(h1s + (size_t)es[e]*1024) + lane*2;
    uint4 a0 = p0[0], a1 = p0[1];
    ACC_U4(a0, 0); ACC_U4(a1, 8);
  }
  #undef ACC_U4

  float ni = norm_in[n];
  uint w[8];
  #pragma unroll
  for (int q = 0; q < 8; ++q)
    w[q] = (uint)f2bf(acc[2*q]*ni) | ((uint)f2bf(acc[2*q+1]*ni) << 16);
  uint4* dp = (uint4*)(x2 + (size_t)n*1024 + lane*16);
  dp[0] = make_uint4(w[0], w[1], w[2], w[3]);
  dp[1] = make_uint4(w[4], w[5], w[6], w[7]);
}

// ---------------- W2 -> bf16 MFMA B-fragments ----------------

__global__ void k_w2frag(const float* __restrict__ W2, ushort* __restrict__ W2F){
  int tid = blockIdx.x*blockDim.x + threadIdx.x;  // 0..4095
  int j = tid & 7, l = (tid >> 3) & 63, i = tid >> 9;
  int g = l >> 4, n = l & 15;
  W2F[tid] = f2bf(W2[(g*8 + j)*128 + i*16 + n]);
}

// ---------------- linear 32->128 + silu via MFMA (x2 node-major) ----------------
// PHASE 0: gates[t][n] = silu(x2@W2+b2).gate_w + gate_b ; Zp[t][bx] = block sum exp(gate)
// PHASE 1: pooled[t][:] += (exp(gate)/Z[t]) * silu(x2@W2+b2)

template<int PHASE>
__global__ void __launch_bounds__(256) k_linear_mfma(
    const ushort* __restrict__ x2, const ushort* __restrict__ W2F,
    const float* __restrict__ b2, const float* __restrict__ gate_w,
    const float* __restrict__ gate_b,
    float* __restrict__ gates, float* __restrict__ Zp,
    const float* __restrict__ Z, float* __restrict__ pooled, int N){
  __shared__ float pool_s[128];
  __shared__ float z_s[4];
  int t = blockIdx.y;
  int tid = threadIdx.x;
  int wave = tid >> 6, lane = tid & 63;
  int g = lane >> 4, n = lane & 15;
  if (PHASE == 1){
    if (tid < 128) pool_s[tid] = 0.f;
    __syncthreads();
  } else {
    if (tid < 4) z_s[tid] = 0.f;
    __syncthreads();
  }
  int tile = blockIdx.x*4 + wave;          // 16-node tile; N = 625*16
  bool active = (tile*16 < N);

  const v8s* W2Fv = (const v8s*)W2F;
  v8s bfrag[8];
  #pragma unroll
  for (int i = 0; i < 8; ++i) bfrag[i] = W2Fv[i*64 + lane];
  v4f acc[8];
  #pragma unroll
  for (int i = 0; i < 8; ++i){
    float bv = b2[i*16 + n];
    acc[i] = (v4f){bv, bv, bv, bv};
  }
  if (active){
    int nb = tile*16;
    const v8s* ap = (const v8s*)(x2 + (size_t)(nb + (lane & 15))*1024 + t*32);
    v8s a = ap[g];
    #pragma unroll
    for (int i = 0; i < 8; ++i)
      acc[i] = __builtin_amdgcn_mfma_f32_16x16x32_bf16(a, bfrag[i], acc[i], 0, 0, 0);
  }
  // C/D layout: value (i,r) = h[node nb + g*4 + r][col i*16 + n]
  if (PHASE == 0){
    if (active){
      float gw8[8];
      #pragma unroll
      for (int i = 0; i < 8; ++i) gw8[i] = gate_w[i*16 + n];
      float gp[4] = {0.f, 0.f, 0.f, 0.f};
      #pragma unroll
      for (int i = 0; i < 8; ++i){
        #pragma unroll
        for (int r = 0; r < 4; ++r) gp[r] += fsilu(acc[i][r]) * gw8[i];
      }
      #pragma unroll
      for (int m = 1; m < 16; m <<= 1){
        #pragma unroll
        for (int r = 0; r < 4; ++r) gp[r] += __shfl_xor(gp[r], m);
      }
      if (n == 0){
        int nb = tile*16;
        float gb = gate_b[0];
        float se = 0.f;
        #pragma unroll
        for (int r = 0; r < 4; ++r){
          float gv = gp[r] + gb;
          gates[(size_t)t*N + nb + g*4 + r] = gv;
          se += __expf(gv);
        }
        se += __shfl_xor(se, 16);
        se += __shfl_xor(se, 32);
        if (lane == 0) z_s[wave] = se;     // block-level partial, no atomics
      }
    }
    __syncthreads();
    if (tid == 0)
      Zp[(size_t)t*GXL + blockIdx.x] = z_s[0] + z_s[1] + z_s[2] + z_s[3];
  } else {
    if (active){
      int nb = tile*16;
      float invZ = __fdividef(1.0f, Z[t]);
      float wn[4];
      #pragma unroll
      for (int r = 0; r < 4; ++r)
        wn[r] = __expf(gates[(size_t)t*N + nb + g*4 + r]) * invZ;
      float cs[8];
      #pragma unroll
      for (int i = 0; i < 8; ++i){
        float c = 0.f;
        #pragma unroll
        for (int r = 0; r < 4; ++r) c += fsilu(acc[i][r]) * wn[r];
        c += __shfl_xor(c, 16);
        c += __shfl_xor(c, 32);
        cs[i] = c;
      }
      if (lane < 16){
        #pragma unroll
        for (int i = 0; i < 8; ++i) atomicAdd(&pool_s[i*16 + lane], cs[i]);
      }
    }
    __syncthreads();
    if (tid < 128) atomicAdd(&pooled[(size_t)t*HID + tid], pool_s[tid]);
  }
}

// ---------------- reduce Z partials: Z[t] = sum_b Zp[t][b] ----------------

__global__ void __launch_bounds__(256) k_zred(const float* __restrict__ Zp,
                                              float* __restrict__ Z){
  __shared__ float red[256];
  int t = blockIdx.x, tid = threadIdx.x;
  float s = 0.f;
  for (int i = tid; i < GXL; i += 256) s += Zp[(size_t)t*GXL + i];
  red[tid] = s; __syncthreads();
  for (int off = 128; off > 0; off >>= 1){
    if (tid < off) red[tid] += red[tid+off];
    __syncthreads();
  }
  if (tid == 0) Z[t] = red[0];
}

// ---------------- GRU + head ----------------

__global__ void __launch_bounds__(384) k_gi(const float* __restrict__ pooled,
                                            const float* __restrict__ W_ih,
                                            const float* __restrict__ b_ih,
                                            float* __restrict__ gi_all){
  __shared__ float ps[HID];
  int t = blockIdx.x, tid = threadIdx.x;   // 384 threads
  if (tid < HID) ps[tid] = pooled[(size_t)t*HID + tid];
  __syncthreads();
  float acc = b_ih[tid];
  const float4* wr = (const float4*)(W_ih + (size_t)tid*HID);
  const float4* p4 = (const float4*)ps;
  #pragma unroll
  for (int q = 0; q < HID/4; ++q){
    float4 wv = wr[q], pv = p4[q];
    acc = fmaf(wv.x, pv.x, acc);
    acc = fmaf(wv.y, pv.y, acc);
    acc = fmaf(wv.z, pv.z, acc);
    acc = fmaf(wv.w, pv.w, acc);
  }
  gi_all[t*384 + tid] = acc;
}

// weights in named float4 registers; gi staged in LDS; h broadcast via LDS.
__global__ void __launch_bounds__(384, 1) k_gru(
    const float* __restrict__ gi_all, const float* __restrict__ W_hh,
    const float* __restrict__ b_hh,
    const float* __restrict__ d1_w, const float* __restrict__ d1_b,
    const float* __restrict__ d2_w, const float* __restrict__ d2_b,
    float* __restrict__ out){
  __shared__ float gi_s[T_FRAMES*3*HID];   // 48 KB
  __shared__ float h_s[HID];
  __shared__ float gh_s[3*HID];
  __shared__ float o1[16];
  int tid = threadIdx.x;  // 384

  for (int i = tid; i < T_FRAMES*3*HID; i += 384) gi_s[i] = gi_all[i];

  const float4* wr = (const float4*)(W_hh + (size_t)tid*HID);  // row o=tid
  #define LDW(i) float4 W##i = wr[i];
  LDW(0) LDW(1) LDW(2) LDW(3) LDW(4) LDW(5) LDW(6) LDW(7)
  LDW(8) LDW(9) LDW(10) LDW(11) LDW(12) LDW(13) LDW(14) LDW(15)
  LDW(16) LDW(17) LDW(18) LDW(19) LDW(20) LDW(21) LDW(22) LDW(23)
  LDW(24) LDW(25) LDW(26) LDW(27) LDW(28) LDW(29) LDW(30) LDW(31)
  #undef LDW
  float bh = b_hh[tid];

  if (tid < HID) h_s[tid] = 0.f;
  __syncthreads();

  for (int t = 0; t < T_FRAMES; ++t){
    const float4* p4 = (const float4*)h_s;
    float acc = bh;
    #define STEP(i) { float4 pv = p4[i]; \
      acc = fmaf(W##i.x, pv.x, acc); acc = fmaf(W##i.y, pv.y, acc); \
      acc = fmaf(W##i.z, pv.z, acc); acc = fmaf(W##i.w, pv.w, acc); }
    STEP(0) STEP(1) STEP(2) STEP(3) STEP(4) STEP(5) STEP(6) STEP(7)
    STEP(8) STEP(9) STEP(10) STEP(11) STEP(12) STEP(13) STEP(14) STEP(15)
    STEP(16) STEP(17) STEP(18) STEP(19) STEP(20) STEP(21) STEP(22) STEP(23)
    STEP(24) STEP(25) STEP(26) STEP(27) STEP(28) STEP(29) STEP(30) STEP(31)
    #undef STEP
    gh_s[tid] = acc;
    __syncthreads();
    if (tid < HID){
      const float* gi = gi_s + t*384;
      float r  = fsigm(gi[tid]       + gh_s[tid]);
      float z  = fsigm(gi[HID+tid]   + gh_s[HID+tid]);
      float nn = ftanh(gi[2*HID+tid] + r*gh_s[2*HID+tid]);
      h_s[tid] = (1.f - z)*nn + z*h_s[tid];
    }
    __syncthreads();
  }
  if (tid < 16){
    float acc = d1_b[tid];
    #pragma unroll 4
    for (int j = 0; j < HID; ++j) acc = fmaf(h_s[j], d1_w[j*16 + tid], acc);
    o1[tid] = fsilu(acc);
  }
  __syncthreads();
  if (tid < 4){
    float acc = d2_b[tid];
    #pragma unroll
    for (int j = 0; j < 16; ++j) acc = fmaf(o1[j], d2_w[j*4 + tid], acc);
    out[tid] = fsigm(fsilu(acc));
  }
}

// ---------------- launch ----------------

extern "C" void kernel_launch(void* const* d_in, const int* in_sizes, int n_in,
                              void* d_out, int out_size, void* d_ws, size_t ws_size,
                              hipStream_t stream){
  const float* features = (const float*)d_in[0];
  const int*   src      = (const int*)  d_in[1];
  const int*   dst      = (const int*)  d_in[2];
  const float* W1       = (const float*)d_in[3];
  const float* b1       = (const float*)d_in[4];
  const float* W2       = (const float*)d_in[5];
  const float* b2       = (const float*)d_in[6];
  const float* gate_w   = (const float*)d_in[7];
  const float* gate_b   = (const float*)d_in[8];
  const float* W_ih     = (const float*)d_in[9];
  const float* W_hh     = (const float*)d_in[10];
  const float* b_ih     = (const float*)d_in[11];
  const float* b_hh     = (const float*)d_in[12];
  const float* d1_w     = (const float*)d_in[13];
  const float* d1_b     = (const float*)d_in[14];
  const float* d2_w     = (const float*)d_in[15];
  const float* d2_b     = (const float*)d_in[16];
  float* out = (float*)d_out;

  const int N = NNODES, E = NEDGES, T = T_FRAMES;

  char* base = (char*)d_ws;
  size_t off = 0;
  auto alloc = [&](size_t bytes)->void*{
    void* p = base + off;
    off = (off + bytes + 255) & ~(size_t)255;
    return p;
  };
  int*    cnt_out = (int*)   alloc((size_t)N*4);
  int*    cnt_in  = (int*)   alloc((size_t)N*4);
  int*    row_ptr = (int*)   alloc((size_t)(N+1)*4);
  int*    cursor  = (int*)   alloc((size_t)N*4);
  float*  norm_o  = (float*) alloc((size_t)N*4);
  float*  norm_i  = (float*) alloc((size_t)N*4);
  int*    es      = (int*)   alloc((size_t)E*4);
  float*  fnT     = (float*) alloc((size_t)N*T*4);
  ushort* h1s     = (ushort*)alloc((size_t)N*T*32*2);
  ushort* x2      = (ushort*)alloc((size_t)N*T*32*2);
  float*  gates   = (float*) alloc((size_t)T*N*4);
  float*  Zp      = (float*) alloc((size_t)T*GXL*4);
  float*  Z       = (float*) alloc((size_t)T*4);
  float*  pooled  = (float*) alloc((size_t)T*HID*4);
  float*  gi_all  = (float*) alloc((size_t)T*3*HID*4);
  ushort* W2F     = (ushort*)alloc((size_t)8*64*8*2);
  (void)ws_size; (void)in_sizes; (void)n_in; (void)out_size;

  hipMemsetAsync(cnt_out, 0, (size_t)N*4, stream);
  hipMemsetAsync(cnt_in,  0, (size_t)N*4, stream);
  hipMemsetAsync(pooled,  0, (size_t)T*HID*4, stream);

  k_degree<<<(E+255)/256, 256, 0, stream>>>(src, dst, cnt_out, cnt_in, E);
  k_norms <<<(N+255)/256, 256, 0, stream>>>(cnt_out, cnt_in, norm_o, norm_i, N);
  k_scan  <<<1, 1024, 0, stream>>>(cnt_in, row_ptr, cursor, N);
  k_fill  <<<(E+255)/256, 256, 0, stream>>>(src, dst, cursor, es, E);

  k_fnT      <<<(N+63)/64, 256, 0, stream>>>(features, norm_o, fnT, N);
  k_gconv1_nm<<<N/4, 256, 0, stream>>>(fnT, row_ptr, es, norm_i, norm_o, W1, b1, h1s, N);
  k_gconv2_nm<<<N/4, 256, 0, stream>>>(h1s, row_ptr, es, norm_i, x2, N);

  k_w2frag<<<16, 256, 0, stream>>>(W2, W2F);

  k_linear_mfma<0><<<dim3(GXL, T), 256, 0, stream>>>(x2, W2F, b2, gate_w, gate_b, gates, Zp, Z, pooled, N);
  k_zred<<<T, 256, 0, stream>>>(Zp, Z);
  k_linear_mfma<1><<<dim3(GXL, T), 256, 0, stream>>>(x2, W2F, b2, gate_w, gate_b, gates, Zp, Z, pooled, N);

  k_gi <<<T, 384, 0, stream>>>(pooled, W_ih, b_ih, gi_all);
  k_gru<<<1, 384, 0, stream>>>(gi_all, W_hh, b_hh, d1_w, d1_b, d2_w, d2_b, out);
}

// Round 7
// 232.482 us; speedup vs baseline: 1.7701x; 1.0395x over previous
//
#include <hip/hip_runtime.h>
#include <stdint.h>

#define T_FRAMES 32
#define NNODES 10000
#define NEDGES 160000
#define HID 128
#define GXL 157   // ceil(625 tiles / 4 waves)

typedef short v8s __attribute__((ext_vector_type(8)));
typedef float v4f __attribute__((ext_vector_type(4)));

static __device__ __forceinline__ ushort f2bf(float f){
  uint32_t u = __float_as_uint(f);
  u += 0x7FFFu + ((u >> 16) & 1u);
  return (ushort)(u >> 16);
}
static __device__ __forceinline__ float bf_lo(uint32_t u){
  return __uint_as_float(u << 16);
}
static __device__ __forceinline__ float bf_hi(uint32_t u){
  return __uint_as_float(u & 0xffff0000u);
}
// fast native transcendentals (v_exp_f32 + v_rcp_f32)
static __device__ __forceinline__ float fsigm(float x){
  return __fdividef(1.0f, 1.0f + __expf(-x));
}
static __device__ __forceinline__ float fsilu(float x){
  return x * fsigm(x);
}
static __device__ __forceinline__ float ftanh(float x){
  return 2.0f * fsigm(2.0f * x) - 1.0f;
}

// ---------------- degree / CSR build ----------------

__global__ void k_degree(const int* __restrict__ src, const int* __restrict__ dst,
                         int* cnt_out, int* cnt_in, int E){
  int e = blockIdx.x*blockDim.x + threadIdx.x;
  if (e < E){
    atomicAdd(&cnt_out[src[e]], 1);
    atomicAdd(&cnt_in[dst[e]], 1);
  }
}

// scan over in-degrees + norms (fused)
__global__ void __launch_bounds__(1024) k_scan(const int* __restrict__ cnt_in,
                                               const int* __restrict__ cnt_out,
                                               int* row_ptr, int* cursor,
                                               float* norm_out, float* norm_in, int N){
  __shared__ int sm[1024];
  __shared__ int carry_s;
  if (threadIdx.x == 0) carry_s = 0;
  __syncthreads();
  for (int base = 0; base < N; base += 1024){
    int i = base + threadIdx.x;
    int v = (i < N) ? cnt_in[i] : 0;
    if (i < N){
      norm_in[i]  = rsqrtf((float)max(v, 1));
      norm_out[i] = rsqrtf((float)max(cnt_out[i], 1));
    }
    sm[threadIdx.x] = v;
    __syncthreads();
    for (int off = 1; off < 1024; off <<= 1){
      int tv = (threadIdx.x >= off) ? sm[threadIdx.x - off] : 0;
      __syncthreads();
      sm[threadIdx.x] += tv;
      __syncthreads();
    }
    int excl = sm[threadIdx.x] - v;
    if (i < N){ row_ptr[i] = carry_s + excl; cursor[i] = carry_s + excl; }
    __syncthreads();
    if (threadIdx.x == 0) carry_s += sm[1023];
    __syncthreads();
  }
  if (threadIdx.x == 0) row_ptr[N] = carry_s;
}

__global__ void k_fill(const int* __restrict__ src, const int* __restrict__ dst,
                       int* cursor, int* es, int E){
  int e = blockIdx.x*blockDim.x + threadIdx.x;
  if (e < E){
    int p = atomicAdd(&cursor[dst[e]], 1);
    es[p] = src[e];
  }
}

// ---------------- transpose features -> node-major, pre-scaled by norm_out ----------------

__global__ void __launch_bounds__(256) k_fnT(const float* __restrict__ feat,
                                             const float* __restrict__ norm_o,
                                             float* __restrict__ fnT, int N){
  __shared__ float sm[32][65];
  int n0 = blockIdx.x*64;
  int tid = threadIdx.x;
  for (int idx = tid; idx < 2048; idx += 256){
    int t = idx >> 6, i = idx & 63;
    int n = n0 + i;
    sm[t][i] = (n < N) ? feat[(size_t)t*N + n] : 0.f;
  }
  __syncthreads();
  for (int idx = tid; idx < 2048; idx += 256){
    int i = idx >> 5, t = idx & 31;
    int n = n0 + i;
    if (n < N) fnT[(size_t)n*32 + t] = sm[t][i] * norm_o[n];
  }
}

// ---------------- gconv1 (node-major): one wave per node ----------------

__global__ void __launch_bounds__(256) k_gconv1_nm(
    const float* __restrict__ fnT, const int* __restrict__ row_ptr,
    const int* __restrict__ es, const float* __restrict__ norm_in,
    const float* __restrict__ norm_out,
    const float* __restrict__ W1, const float* __restrict__ b1,
    ushort* __restrict__ h1s, int N){
  __shared__ float w1s[32], b1s[32];
  int tid = threadIdx.x;
  if (tid < 32){ w1s[tid] = W1[tid]; b1s[tid] = b1[tid]; }
  __syncthreads();
  int n = blockIdx.x*4 + (tid >> 6);          // N % 4 == 0
  int lane = tid & 63;
  int ep = lane >> 5, t = lane & 31;
  int s = row_ptr[n], d = row_ptr[n+1];
  float acc = 0.f;
  for (int e = s + ep; e < d; e += 2)
    acc += fnT[(size_t)es[e]*32 + t];
  acc += __shfl_xor(acc, 32);
  float x1 = acc * norm_in[n];
  float x1p = __shfl(x1, lane >> 1);          // lane l gets x1[t = l>>1]
  float no = norm_out[n];
  int j0 = (lane & 1) * 16;
  uint w[8];
  #pragma unroll
  for (int q = 0; q < 8; ++q){
    float h0 = fsilu(fmaf(x1p, w1s[j0+2*q],   b1s[j0+2*q]))   * no;
    float h1 = fsilu(fmaf(x1p, w1s[j0+2*q+1], b1s[j0+2*q+1])) * no;
    w[q] = (uint)f2bf(h0) | ((uint)f2bf(h1) << 16);
  }
  uint4* dp = (uint4*)(h1s + (size_t)n*1024 + lane*16);
  dp[0] = make_uint4(w[0], w[1], w[2], w[3]);
  dp[1] = make_uint4(w[4], w[5], w[6], w[7]);
}

// ---------------- gconv2 (node-major): one wave per node ----------------

__global__ void __launch_bounds__(256) k_gconv2_nm(
    const ushort* __restrict__ h1s, const int* __restrict__ row_ptr,
    const int* __restrict__ es, const float* __restrict__ norm_in,
    ushort* __restrict__ x2, int N){
  int tid = threadIdx.x;
  int n = blockIdx.x*4 + (tid >> 6);
  int lane = tid & 63;
  int s = row_ptr[n], d = row_ptr[n+1];
  float acc[16];
  #pragma unroll
  for (int i = 0; i < 16; ++i) acc[i] = 0.f;

  #define ACC_U4(v, base) do { \
    acc[(base)+0] += bf_lo((v).x); acc[(base)+1] += bf_hi((v).x); \
    acc[(base)+2] += bf_lo((v).y); acc[(base)+3] += bf_hi((v).y); \
    acc[(base)+4] += bf_lo((v).z); acc[(base)+5] += bf_hi((v).z); \
    acc[(base)+6] += bf_lo((v).w); acc[(base)+7] += bf_hi((v).w); \
  } while(0)

  int e = s;
  for (; e + 1 < d; e += 2){
    const uint4* p0 = (const uint4*)(h1s + (size_t)es[e]  *1024) + lane*2;
    const uint4* p1 = (const uint4*)(h1s + (size_t)es[e+1]*1024) + lane*2;
    uint4 a0 = p0[0], a1 = p0[1];
    uint4 c0 = p1[0], c1 = p1[1];
    ACC_U4(a0, 0); ACC_U4(a1, 8);
    ACC_U4(c0, 0); ACC_U4(c1, 8);
  }
  if (e < d){
    const uint4* p0 = (const uint4*)(h1s + (size_t)es[e]*1024) + lane*2;
    uint4 a0 = p0[0], a1 = p0[1];
    ACC_U4(a0, 0); ACC_U4(a1, 8);
  }
  #undef ACC_U4

  float ni = norm_in[n];
  uint w[8];
  #pragma unroll
  for (int q = 0; q < 8; ++q)
    w[q] = (uint)f2bf(acc[2*q]*ni) | ((uint)f2bf(acc[2*q+1]*ni) << 16);
  uint4* dp = (uint4*)(x2 + (size_t)n*1024 + lane*16);
  dp[0] = make_uint4(w[0], w[1], w[2], w[3]);
  dp[1] = make_uint4(w[4], w[5], w[6], w[7]);
}

// ---------------- W2 -> bf16 MFMA B-fragments ----------------

__global__ void k_w2frag(const float* __restrict__ W2, ushort* __restrict__ W2F){
  int tid = blockIdx.x*blockDim.x + threadIdx.x;  // 0..4095
  int j = tid & 7, l = (tid >> 3) & 63, i = tid >> 9;
  int g = l >> 4, n = l & 15;
  W2F[tid] = f2bf(W2[(g*8 + j)*128 + i*16 + n]);
}

// ---------------- linear 32->128 + silu via MFMA (x2 node-major) ----------------

template<int PHASE>
__global__ void __launch_bounds__(256) k_linear_mfma(
    const ushort* __restrict__ x2, const ushort* __restrict__ W2F,
    const float* __restrict__ b2, const float* __restrict__ gate_w,
    const float* __restrict__ gate_b,
    float* __restrict__ gates, float* __restrict__ Zp,
    const float* __restrict__ Z, float* __restrict__ pooled, int N){
  __shared__ float pool_s[128];
  __shared__ float z_s[4];
  int t = blockIdx.y;
  int tid = threadIdx.x;
  int wave = tid >> 6, lane = tid & 63;
  int g = lane >> 4, n = lane & 15;
  if (PHASE == 1){
    if (tid < 128) pool_s[tid] = 0.f;
    __syncthreads();
  } else {
    if (tid < 4) z_s[tid] = 0.f;
    __syncthreads();
  }
  int tile = blockIdx.x*4 + wave;          // 16-node tile; N = 625*16
  bool active = (tile*16 < N);

  const v8s* W2Fv = (const v8s*)W2F;
  v8s bfrag[8];
  #pragma unroll
  for (int i = 0; i < 8; ++i) bfrag[i] = W2Fv[i*64 + lane];
  v4f acc[8];
  #pragma unroll
  for (int i = 0; i < 8; ++i){
    float bv = b2[i*16 + n];
    acc[i] = (v4f){bv, bv, bv, bv};
  }
  if (active){
    int nb = tile*16;
    const v8s* ap = (const v8s*)(x2 + (size_t)(nb + (lane & 15))*1024 + t*32);
    v8s a = ap[g];
    #pragma unroll
    for (int i = 0; i < 8; ++i)
      acc[i] = __builtin_amdgcn_mfma_f32_16x16x32_bf16(a, bfrag[i], acc[i], 0, 0, 0);
  }
  // C/D layout: value (i,r) = h[node nb + g*4 + r][col i*16 + n]
  if (PHASE == 0){
    if (active){
      float gw8[8];
      #pragma unroll
      for (int i = 0; i < 8; ++i) gw8[i] = gate_w[i*16 + n];
      float gp[4] = {0.f, 0.f, 0.f, 0.f};
      #pragma unroll
      for (int i = 0; i < 8; ++i){
        #pragma unroll
        for (int r = 0; r < 4; ++r) gp[r] += fsilu(acc[i][r]) * gw8[i];
      }
      #pragma unroll
      for (int m = 1; m < 16; m <<= 1){
        #pragma unroll
        for (int r = 0; r < 4; ++r) gp[r] += __shfl_xor(gp[r], m);
      }
      if (n == 0){
        int nb = tile*16;
        float gb = gate_b[0];
        float se = 0.f;
        #pragma unroll
        for (int r = 0; r < 4; ++r){
          float gv = gp[r] + gb;
          gates[(size_t)t*N + nb + g*4 + r] = gv;
          se += __expf(gv);
        }
        se += __shfl_xor(se, 16);
        se += __shfl_xor(se, 32);
        if (lane == 0) z_s[wave] = se;     // block-level partial, no atomics
      }
    }
    __syncthreads();
    if (tid == 0)
      Zp[(size_t)t*GXL + blockIdx.x] = z_s[0] + z_s[1] + z_s[2] + z_s[3];
  } else {
    if (active){
      int nb = tile*16;
      float invZ = __fdividef(1.0f, Z[t]);
      float wn[4];
      #pragma unroll
      for (int r = 0; r < 4; ++r)
        wn[r] = __expf(gates[(size_t)t*N + nb + g*4 + r]) * invZ;
      float cs[8];
      #pragma unroll
      for (int i = 0; i < 8; ++i){
        float c = 0.f;
        #pragma unroll
        for (int r = 0; r < 4; ++r) c += fsilu(acc[i][r]) * wn[r];
        c += __shfl_xor(c, 16);
        c += __shfl_xor(c, 32);
        cs[i] = c;
      }
      if (lane < 16){
        #pragma unroll
        for (int i = 0; i < 8; ++i) atomicAdd(&pool_s[i*16 + lane], cs[i]);
      }
    }
    __syncthreads();
    if (tid < 128) atomicAdd(&pooled[(size_t)t*HID + tid], pool_s[tid]);
  }
}

// ---------------- reduce Z partials ----------------

__global__ void __launch_bounds__(256) k_zred(const float* __restrict__ Zp,
                                              float* __restrict__ Z){
  __shared__ float red[256];
  int t = blockIdx.x, tid = threadIdx.x;
  float s = 0.f;
  for (int i = tid; i < GXL; i += 256) s += Zp[(size_t)t*GXL + i];
  red[tid] = s; __syncthreads();
  for (int off = 128; off > 0; off >>= 1){
    if (tid < off) red[tid] += red[tid+off];
    __syncthreads();
  }
  if (tid == 0) Z[t] = red[0];
}

// ---------------- GRU + head ----------------

__global__ void __launch_bounds__(384) k_gi(const float* __restrict__ pooled,
                                            const float* __restrict__ W_ih,
                                            const float* __restrict__ b_ih,
                                            float* __restrict__ gi_all){
  __shared__ float ps[HID];
  int t = blockIdx.x, tid = threadIdx.x;   // 384 threads
  if (tid < HID) ps[tid] = pooled[(size_t)t*HID + tid];
  __syncthreads();
  float acc = b_ih[tid];
  const float4* wr = (const float4*)(W_ih + (size_t)tid*HID);
  const float4* p4 = (const float4*)ps;
  #pragma unroll
  for (int q = 0; q < HID/4; ++q){
    float4 wv = wr[q], pv = p4[q];
    acc = fmaf(wv.x, pv.x, acc);
    acc = fmaf(wv.y, pv.y, acc);
    acc = fmaf(wv.z, pv.z, acc);
    acc = fmaf(wv.w, pv.w, acc);
  }
  gi_all[t*384 + tid] = acc;
}

// split-K GRU: 768 threads, each owns 64 weight floats (16 float4) in registers.
// thread tid: output o = tid (mod 384), K-half = tid/384. Partials combined in LDS.
__global__ void __launch_bounds__(768) k_gru(
    const float* __restrict__ gi_all, const float* __restrict__ W_hh,
    const float* __restrict__ b_hh,
    const float* __restrict__ d1_w, const float* __restrict__ d1_b,
    const float* __restrict__ d2_w, const float* __restrict__ d2_b,
    float* __restrict__ out){
  __shared__ float gi_s[T_FRAMES*3*HID];   // 48 KB
  __shared__ float ps[2*384];              // split-K partials
  __shared__ float h_s[HID];
  __shared__ float o1[16];
  int tid = threadIdx.x;  // 768
  int half = (tid >= 384) ? 1 : 0;
  int o = tid - half*384;

  for (int i = tid; i < T_FRAMES*3*HID; i += 768) gi_s[i] = gi_all[i];

  const float4* wr = (const float4*)(W_hh + (size_t)o*HID + half*64);  // 16 vec4
  #define LDW(i) float4 W##i = wr[i];
  LDW(0) LDW(1) LDW(2) LDW(3) LDW(4) LDW(5) LDW(6) LDW(7)
  LDW(8) LDW(9) LDW(10) LDW(11) LDW(12) LDW(13) LDW(14) LDW(15)
  #undef LDW
  float bh2 = half ? 0.f : b_hh[o];

  if (tid < HID) h_s[tid] = 0.f;
  __syncthreads();

  for (int t = 0; t < T_FRAMES; ++t){
    const float4* p4 = (const float4*)h_s + half*16;
    float acc = bh2;
    #define STEP(i) { float4 pv = p4[i]; \
      acc = fmaf(W##i.x, pv.x, acc); acc = fmaf(W##i.y, pv.y, acc); \
      acc = fmaf(W##i.z, pv.z, acc); acc = fmaf(W##i.w, pv.w, acc); }
    STEP(0) STEP(1) STEP(2) STEP(3) STEP(4) STEP(5) STEP(6) STEP(7)
    STEP(8) STEP(9) STEP(10) STEP(11) STEP(12) STEP(13) STEP(14) STEP(15)
    #undef STEP
    ps[tid] = acc;
    __syncthreads();
    if (tid < HID){
      const float* gi = gi_s + t*384;
      float ghr = ps[tid]       + ps[384+tid];
      float ghz = ps[128+tid]   + ps[512+tid];
      float ghn = ps[256+tid]   + ps[640+tid];
      float r  = fsigm(gi[tid]       + ghr);
      float z  = fsigm(gi[HID+tid]   + ghz);
      float nn = ftanh(gi[2*HID+tid] + r*ghn);
      h_s[tid] = (1.f - z)*nn + z*h_s[tid];
    }
    __syncthreads();
  }
  if (tid < 16){
    float acc = d1_b[tid];
    #pragma unroll 4
    for (int j = 0; j < HID; ++j) acc = fmaf(h_s[j], d1_w[j*16 + tid], acc);
    o1[tid] = fsilu(acc);
  }
  __syncthreads();
  if (tid < 4){
    float acc = d2_b[tid];
    #pragma unroll
    for (int j = 0; j < 16; ++j) acc = fmaf(o1[j], d2_w[j*4 + tid], acc);
    out[tid] = fsigm(fsilu(acc));
  }
}

// ---------------- launch ----------------

extern "C" void kernel_launch(void* const* d_in, const int* in_sizes, int n_in,
                              void* d_out, int out_size, void* d_ws, size_t ws_size,
                              hipStream_t stream){
  const float* features = (const float*)d_in[0];
  const int*   src      = (const int*)  d_in[1];
  const int*   dst      = (const int*)  d_in[2];
  const float* W1       = (const float*)d_in[3];
  const float* b1       = (const float*)d_in[4];
  const float* W2       = (const float*)d_in[5];
  const float* b2       = (const float*)d_in[6];
  const float* gate_w   = (const float*)d_in[7];
  const float* gate_b   = (const float*)d_in[8];
  const float* W_ih     = (const float*)d_in[9];
  const float* W_hh     = (const float*)d_in[10];
  const float* b_ih     = (const float*)d_in[11];
  const float* b_hh     = (const float*)d_in[12];
  const float* d1_w     = (const float*)d_in[13];
  const float* d1_b     = (const float*)d_in[14];
  const float* d2_w     = (const float*)d_in[15];
  const float* d2_b     = (const float*)d_in[16];
  float* out = (float*)d_out;

  const int N = NNODES, E = NEDGES, T = T_FRAMES;

  char* base = (char*)d_ws;
  size_t off = 0;
  auto alloc = [&](size_t bytes)->void*{
    void* p = base + off;
    off = (off + bytes + 255) & ~(size_t)255;
    return p;
  };
  // zero-init group (one memset): cnt_out | cnt_in | pooled
  int*    cnt_out = (int*)   alloc((size_t)N*4);
  int*    cnt_in  = (int*)   alloc((size_t)N*4);
  float*  pooled  = (float*) alloc((size_t)T*HID*4);
  size_t zero_span = off;                      // bytes from base to end of pooled
  int*    row_ptr = (int*)   alloc((size_t)(N+1)*4);
  int*    cursor  = (int*)   alloc((size_t)N*4);
  float*  norm_o  = (float*) alloc((size_t)N*4);
  float*  norm_i  = (float*) alloc((size_t)N*4);
  int*    es      = (int*)   alloc((size_t)E*4);
  float*  fnT     = (float*) alloc((size_t)N*T*4);
  ushort* h1s     = (ushort*)alloc((size_t)N*T*32*2);
  ushort* x2      = (ushort*)alloc((size_t)N*T*32*2);
  float*  gates   = (float*) alloc((size_t)T*N*4);
  float*  Zp      = (float*) alloc((size_t)T*GXL*4);
  float*  Z       = (float*) alloc((size_t)T*4);
  float*  gi_all  = (float*) alloc((size_t)T*3*HID*4);
  ushort* W2F     = (ushort*)alloc((size_t)8*64*8*2);
  (void)ws_size; (void)in_sizes; (void)n_in; (void)out_size;

  hipMemsetAsync(d_ws, 0, zero_span, stream);

  k_degree<<<(E+255)/256, 256, 0, stream>>>(src, dst, cnt_out, cnt_in, E);
  k_scan  <<<1, 1024, 0, stream>>>(cnt_in, cnt_out, row_ptr, cursor, norm_o, norm_i, N);
  k_fill  <<<(E+255)/256, 256, 0, stream>>>(src, dst, cursor, es, E);

  k_fnT      <<<(N+63)/64, 256, 0, stream>>>(features, norm_o, fnT, N);
  k_gconv1_nm<<<N/4, 256, 0, stream>>>(fnT, row_ptr, es, norm_i, norm_o, W1, b1, h1s, N);
  k_gconv2_nm<<<N/4, 256, 0, stream>>>(h1s, row_ptr, es, norm_i, x2, N);

  k_w2frag<<<16, 256, 0, stream>>>(W2, W2F);

  k_linear_mfma<0><<<dim3(GXL, T), 256, 0, stream>>>(x2, W2F, b2, gate_w, gate_b, gates, Zp, Z, pooled, N);
  k_zred<<<T, 256, 0, stream>>>(Zp, Z);
  k_linear_mfma<1><<<dim3(GXL, T), 256, 0, stream>>>(x2, W2F, b2, gate_w, gate_b, gates, Zp, Z, pooled, N);

  k_gi <<<T, 384, 0, stream>>>(pooled, W_ih, b_ih, gi_all);
  k_gru<<<1, 768, 0, stream>>>(gi_all, W_hh, b_hh, d1_w, d1_b, d2_w, d2_b, out);
}

// Round 8
// 220.606 us; speedup vs baseline: 1.8654x; 1.0538x over previous
//
#include <hip/hip_runtime.h>
#include <stdint.h>

#define T_FRAMES 32
#define NNODES 10000
#define NEDGES 160000
#define HID 128
#define GXL 157   // ceil(625 tiles / 4 waves)

typedef short v8s __attribute__((ext_vector_type(8)));
typedef float v4f __attribute__((ext_vector_type(4)));

static __device__ __forceinline__ ushort f2bf(float f){
  uint32_t u = __float_as_uint(f);
  u += 0x7FFFu + ((u >> 16) & 1u);
  return (ushort)(u >> 16);
}
static __device__ __forceinline__ float bf_lo(uint32_t u){
  return __uint_as_float(u << 16);
}
static __device__ __forceinline__ float bf_hi(uint32_t u){
  return __uint_as_float(u & 0xffff0000u);
}
// fast native transcendentals (v_exp_f32 + v_rcp_f32)
static __device__ __forceinline__ float fsigm(float x){
  return __fdividef(1.0f, 1.0f + __expf(-x));
}
static __device__ __forceinline__ float fsilu(float x){
  return x * fsigm(x);
}
static __device__ __forceinline__ float ftanh(float x){
  return 2.0f * fsigm(2.0f * x) - 1.0f;
}

// ---------------- degree / CSR build ----------------

__global__ void k_degree(const int* __restrict__ src, const int* __restrict__ dst,
                         int* cnt_out, int* cnt_in, int E){
  int e = blockIdx.x*blockDim.x + threadIdx.x;
  if (e < E){
    atomicAdd(&cnt_out[src[e]], 1);
    atomicAdd(&cnt_in[dst[e]], 1);
  }
}

// scan over in-degrees + norms (fused), wave-shfl based
__global__ void __launch_bounds__(1024) k_scan(const int* __restrict__ cnt_in,
                                               const int* __restrict__ cnt_out,
                                               int* row_ptr, int* cursor,
                                               float* norm_out, float* norm_in, int N){
  __shared__ int wsum[16];
  __shared__ int carry_s, total_s;
  int tid = threadIdx.x;
  int lane = tid & 63, wid = tid >> 6;
  if (tid == 0) carry_s = 0;
  __syncthreads();
  for (int base = 0; base < N; base += 1024){
    int i = base + tid;
    int v = (i < N) ? cnt_in[i] : 0;
    if (i < N){
      norm_in[i]  = rsqrtf((float)max(v, 1));
      norm_out[i] = rsqrtf((float)max(cnt_out[i], 1));
    }
    int x = v;
    #pragma unroll
    for (int off = 1; off < 64; off <<= 1){
      int y = __shfl_up(x, off);
      if (lane >= off) x += y;
    }
    if (lane == 63) wsum[wid] = x;
    __syncthreads();
    if (tid == 0){
      int run = 0;
      #pragma unroll
      for (int w = 0; w < 16; ++w){ int tv = wsum[w]; wsum[w] = run; run += tv; }
      total_s = run;
    }
    __syncthreads();
    int excl = carry_s + wsum[wid] + x - v;
    if (i < N){ row_ptr[i] = excl; cursor[i] = excl; }
    __syncthreads();
    if (tid == 0) carry_s += total_s;
  }
  __syncthreads();
  if (tid == 0) row_ptr[N] = carry_s;
}

__global__ void k_fill(const int* __restrict__ src, const int* __restrict__ dst,
                       int* cursor, int* es, int E){
  int e = blockIdx.x*blockDim.x + threadIdx.x;
  if (e < E){
    int p = atomicAdd(&cursor[dst[e]], 1);
    es[p] = src[e];
  }
}

// ---------------- transpose features -> node-major, pre-scaled by norm_out ----------------

__global__ void __launch_bounds__(256) k_fnT(const float* __restrict__ feat,
                                             const float* __restrict__ norm_o,
                                             float* __restrict__ fnT, int N){
  __shared__ float sm[32][65];
  int n0 = blockIdx.x*64;
  int tid = threadIdx.x;
  for (int idx = tid; idx < 2048; idx += 256){
    int t = idx >> 6, i = idx & 63;
    int n = n0 + i;
    sm[t][i] = (n < N) ? feat[(size_t)t*N + n] : 0.f;
  }
  __syncthreads();
  for (int idx = tid; idx < 2048; idx += 256){
    int i = idx >> 5, t = idx & 31;
    int n = n0 + i;
    if (n < N) fnT[(size_t)n*32 + t] = sm[t][i] * norm_o[n];
  }
}

// ---------------- gconv1 (node-major): one wave per node ----------------

__global__ void __launch_bounds__(256) k_gconv1_nm(
    const float* __restrict__ fnT, const int* __restrict__ row_ptr,
    const int* __restrict__ es, const float* __restrict__ norm_in,
    const float* __restrict__ norm_out,
    const float* __restrict__ W1, const float* __restrict__ b1,
    ushort* __restrict__ h1s, int N){
  __shared__ float w1s[32], b1s[32];
  int tid = threadIdx.x;
  if (tid < 32){ w1s[tid] = W1[tid]; b1s[tid] = b1[tid]; }
  __syncthreads();
  int n = blockIdx.x*4 + (tid >> 6);          // N % 4 == 0
  int lane = tid & 63;
  int ep = lane >> 5, t = lane & 31;
  int s = row_ptr[n], d = row_ptr[n+1];
  float acc = 0.f;
  int e = s + ep;
  for (; e + 6 < d; e += 8){
    float v0 = fnT[(size_t)es[e]  *32 + t];
    float v1 = fnT[(size_t)es[e+2]*32 + t];
    float v2 = fnT[(size_t)es[e+4]*32 + t];
    float v3 = fnT[(size_t)es[e+6]*32 + t];
    acc += v0 + v1 + v2 + v3;
  }
  for (; e < d; e += 2)
    acc += fnT[(size_t)es[e]*32 + t];
  acc += __shfl_xor(acc, 32);
  float x1 = acc * norm_in[n];
  float x1p = __shfl(x1, lane >> 1);          // lane l gets x1[t = l>>1]
  float no = norm_out[n];
  int j0 = (lane & 1) * 16;
  uint w[8];
  #pragma unroll
  for (int q = 0; q < 8; ++q){
    float h0 = fsilu(fmaf(x1p, w1s[j0+2*q],   b1s[j0+2*q]))   * no;
    float h1 = fsilu(fmaf(x1p, w1s[j0+2*q+1], b1s[j0+2*q+1])) * no;
    w[q] = (uint)f2bf(h0) | ((uint)f2bf(h1) << 16);
  }
  uint4* dp = (uint4*)(h1s + (size_t)n*1024 + lane*16);
  dp[0] = make_uint4(w[0], w[1], w[2], w[3]);
  dp[1] = make_uint4(w[4], w[5], w[6], w[7]);
}

// ---------------- gconv2 (node-major): one wave per node, 4-edge unroll ----------------

__global__ void __launch_bounds__(256) k_gconv2_nm(
    const ushort* __restrict__ h1s, const int* __restrict__ row_ptr,
    const int* __restrict__ es, const float* __restrict__ norm_in,
    ushort* __restrict__ x2, int N){
  int tid = threadIdx.x;
  int n = blockIdx.x*4 + (tid >> 6);
  int lane = tid & 63;
  int s = row_ptr[n], d = row_ptr[n+1];
  float acc[16];
  #pragma unroll
  for (int i = 0; i < 16; ++i) acc[i] = 0.f;

  #define ACC_U4(v, base) do { \
    acc[(base)+0] += bf_lo((v).x); acc[(base)+1] += bf_hi((v).x); \
    acc[(base)+2] += bf_lo((v).y); acc[(base)+3] += bf_hi((v).y); \
    acc[(base)+4] += bf_lo((v).z); acc[(base)+5] += bf_hi((v).z); \
    acc[(base)+6] += bf_lo((v).w); acc[(base)+7] += bf_hi((v).w); \
  } while(0)

  int e = s;
  for (; e + 3 < d; e += 4){
    const uint4* p0 = (const uint4*)(h1s + (size_t)es[e]  *1024) + lane*2;
    const uint4* p1 = (const uint4*)(h1s + (size_t)es[e+1]*1024) + lane*2;
    const uint4* p2 = (const uint4*)(h1s + (size_t)es[e+2]*1024) + lane*2;
    const uint4* p3 = (const uint4*)(h1s + (size_t)es[e+3]*1024) + lane*2;
    uint4 a0 = p0[0], a1 = p0[1];
    uint4 b0 = p1[0], b1 = p1[1];
    uint4 c0 = p2[0], c1 = p2[1];
    uint4 d0 = p3[0], d1 = p3[1];
    ACC_U4(a0, 0); ACC_U4(a1, 8);
    ACC_U4(b0, 0); ACC_U4(b1, 8);
    ACC_U4(c0, 0); ACC_U4(c1, 8);
    ACC_U4(d0, 0); ACC_U4(d1, 8);
  }
  for (; e < d; ++e){
    const uint4* p0 = (const uint4*)(h1s + (size_t)es[e]*1024) + lane*2;
    uint4 a0 = p0[0], a1 = p0[1];
    ACC_U4(a0, 0); ACC_U4(a1, 8);
  }
  #undef ACC_U4

  float ni = norm_in[n];
  uint w[8];
  #pragma unroll
  for (int q = 0; q < 8; ++q)
    w[q] = (uint)f2bf(acc[2*q]*ni) | ((uint)f2bf(acc[2*q+1]*ni) << 16);
  uint4* dp = (uint4*)(x2 + (size_t)n*1024 + lane*16);
  dp[0] = make_uint4(w[0], w[1], w[2], w[3]);
  dp[1] = make_uint4(w[4], w[5], w[6], w[7]);
}

// ---------------- W2 -> bf16 MFMA B-fragments ----------------

__global__ void k_w2frag(const float* __restrict__ W2, ushort* __restrict__ W2F){
  int tid = blockIdx.x*blockDim.x + threadIdx.x;  // 0..4095
  int j = tid & 7, l = (tid >> 3) & 63, i = tid >> 9;
  int g = l >> 4, n = l & 15;
  W2F[tid] = f2bf(W2[(g*8 + j)*128 + i*16 + n]);
}

// ---------------- linear 32->128 + silu via MFMA (x2 node-major) ----------------
// PHASE 0: gates[t][n] = silu(x2@W2+b2).gate_w + gate_b ; Zp[t][bx] = block sum exp(gate)
// PHASE 1: pooled[t][:] += (exp(gate)/Z[t]) * silu(x2@W2+b2), Z reduced in-wave from Zp

template<int PHASE>
__global__ void __launch_bounds__(256) k_linear_mfma(
    const ushort* __restrict__ x2, const ushort* __restrict__ W2F,
    const float* __restrict__ b2, const float* __restrict__ gate_w,
    const float* __restrict__ gate_b,
    float* __restrict__ gates, float* __restrict__ Zp,
    float* __restrict__ pooled, int N){
  __shared__ float pool_s[128];
  __shared__ float z_s[4];
  int t = blockIdx.y;
  int tid = threadIdx.x;
  int wave = tid >> 6, lane = tid & 63;
  int g = lane >> 4, n = lane & 15;
  if (PHASE == 1){
    if (tid < 128) pool_s[tid] = 0.f;
    __syncthreads();
  } else {
    if (tid < 4) z_s[tid] = 0.f;
    __syncthreads();
  }
  int tile = blockIdx.x*4 + wave;          // 16-node tile; N = 625*16
  bool active = (tile*16 < N);

  // PHASE 1: per-wave redundant reduce of Zp -> invZ (no barrier needed)
  float invZ = 0.f;
  if (PHASE == 1){
    float zs = 0.f;
    for (int i = lane; i < GXL; i += 64) zs += Zp[(size_t)t*GXL + i];
    #pragma unroll
    for (int m = 32; m; m >>= 1) zs += __shfl_xor(zs, m);
    invZ = __fdividef(1.0f, zs);
  }

  const v8s* W2Fv = (const v8s*)W2F;
  v8s bfrag[8];
  #pragma unroll
  for (int i = 0; i < 8; ++i) bfrag[i] = W2Fv[i*64 + lane];
  v4f acc[8];
  #pragma unroll
  for (int i = 0; i < 8; ++i){
    float bv = b2[i*16 + n];
    acc[i] = (v4f){bv, bv, bv, bv};
  }
  if (active){
    int nb = tile*16;
    const v8s* ap = (const v8s*)(x2 + (size_t)(nb + (lane & 15))*1024 + t*32);
    v8s a = ap[g];
    #pragma unroll
    for (int i = 0; i < 8; ++i)
      acc[i] = __builtin_amdgcn_mfma_f32_16x16x32_bf16(a, bfrag[i], acc[i], 0, 0, 0);
  }
  // C/D layout: value (i,r) = h[node nb + g*4 + r][col i*16 + n]
  if (PHASE == 0){
    if (active){
      float gw8[8];
      #pragma unroll
      for (int i = 0; i < 8; ++i) gw8[i] = gate_w[i*16 + n];
      float gp[4] = {0.f, 0.f, 0.f, 0.f};
      #pragma unroll
      for (int i = 0; i < 8; ++i){
        #pragma unroll
        for (int r = 0; r < 4; ++r) gp[r] += fsilu(acc[i][r]) * gw8[i];
      }
      #pragma unroll
      for (int m = 1; m < 16; m <<= 1){
        #pragma unroll
        for (int r = 0; r < 4; ++r) gp[r] += __shfl_xor(gp[r], m);
      }
      if (n == 0){
        int nb = tile*16;
        float gb = gate_b[0];
        float se = 0.f;
        #pragma unroll
        for (int r = 0; r < 4; ++r){
          float gv = gp[r] + gb;
          gates[(size_t)t*N + nb + g*4 + r] = gv;
          se += __expf(gv);
        }
        se += __shfl_xor(se, 16);
        se += __shfl_xor(se, 32);
        if (lane == 0) z_s[wave] = se;     // block-level partial, no atomics
      }
    }
    __syncthreads();
    if (tid == 0)
      Zp[(size_t)t*GXL + blockIdx.x] = z_s[0] + z_s[1] + z_s[2] + z_s[3];
  } else {
    if (active){
      int nb = tile*16;
      float wn[4];
      #pragma unroll
      for (int r = 0; r < 4; ++r)
        wn[r] = __expf(gates[(size_t)t*N + nb + g*4 + r]) * invZ;
      float cs[8];
      #pragma unroll
      for (int i = 0; i < 8; ++i){
        float c = 0.f;
        #pragma unroll
        for (int r = 0; r < 4; ++r) c += fsilu(acc[i][r]) * wn[r];
        c += __shfl_xor(c, 16);
        c += __shfl_xor(c, 32);
        cs[i] = c;
      }
      if (lane < 16){
        #pragma unroll
        for (int i = 0; i < 8; ++i) atomicAdd(&pool_s[i*16 + lane], cs[i]);
      }
    }
    __syncthreads();
    if (tid < 128) atomicAdd(&pooled[(size_t)t*HID + tid], pool_s[tid]);
  }
}

// ---------------- GRU + head ----------------

__global__ void __launch_bounds__(384) k_gi(const float* __restrict__ pooled,
                                            const float* __restrict__ W_ih,
                                            const float* __restrict__ b_ih,
                                            float* __restrict__ gi_all){
  __shared__ float ps[HID];
  int t = blockIdx.x, tid = threadIdx.x;   // 384 threads
  if (tid < HID) ps[tid] = pooled[(size_t)t*HID + tid];
  __syncthreads();
  float acc = b_ih[tid];
  const float4* wr = (const float4*)(W_ih + (size_t)tid*HID);
  const float4* p4 = (const float4*)ps;
  #pragma unroll
  for (int q = 0; q < HID/4; ++q){
    float4 wv = wr[q], pv = p4[q];
    acc = fmaf(wv.x, pv.x, acc);
    acc = fmaf(wv.y, pv.y, acc);
    acc = fmaf(wv.z, pv.z, acc);
    acc = fmaf(wv.w, pv.w, acc);
  }
  gi_all[t*384 + tid] = acc;
}

// split-K GRU: 768 threads, each owns 64 weight floats (16 float4) in registers.
__global__ void __launch_bounds__(768) k_gru(
    const float* __restrict__ gi_all, const float* __restrict__ W_hh,
    const float* __restrict__ b_hh,
    const float* __restrict__ d1_w, const float* __restrict__ d1_b,
    const float* __restrict__ d2_w, const float* __restrict__ d2_b,
    float* __restrict__ out){
  __shared__ float gi_s[T_FRAMES*3*HID];   // 48 KB
  __shared__ float ps[2*384];              // split-K partials
  __shared__ float h_s[HID];
  __shared__ float o1[16];
  int tid = threadIdx.x;  // 768
  int half = (tid >= 384) ? 1 : 0;
  int o = tid - half*384;

  for (int i = tid; i < T_FRAMES*3*HID; i += 768) gi_s[i] = gi_all[i];

  const float4* wr = (const float4*)(W_hh + (size_t)o*HID + half*64);  // 16 vec4
  #define LDW(i) float4 W##i = wr[i];
  LDW(0) LDW(1) LDW(2) LDW(3) LDW(4) LDW(5) LDW(6) LDW(7)
  LDW(8) LDW(9) LDW(10) LDW(11) LDW(12) LDW(13) LDW(14) LDW(15)
  #undef LDW
  float bh2 = half ? 0.f : b_hh[o];

  if (tid < HID) h_s[tid] = 0.f;
  __syncthreads();

  for (int t = 0; t < T_FRAMES; ++t){
    const float4* p4 = (const float4*)h_s + half*16;
    float acc = bh2;
    #define STEP(i) { float4 pv = p4[i]; \
      acc = fmaf(W##i.x, pv.x, acc); acc = fmaf(W##i.y, pv.y, acc); \
      acc = fmaf(W##i.z, pv.z, acc); acc = fmaf(W##i.w, pv.w, acc); }
    STEP(0) STEP(1) STEP(2) STEP(3) STEP(4) STEP(5) STEP(6) STEP(7)
    STEP(8) STEP(9) STEP(10) STEP(11) STEP(12) STEP(13) STEP(14) STEP(15)
    #undef STEP
    ps[tid] = acc;
    __syncthreads();
    if (tid < HID){
      const float* gi = gi_s + t*384;
      float ghr = ps[tid]       + ps[384+tid];
      float ghz = ps[128+tid]   + ps[512+tid];
      float ghn = ps[256+tid]   + ps[640+tid];
      float r  = fsigm(gi[tid]       + ghr);
      float z  = fsigm(gi[HID+tid]   + ghz);
      float nn = ftanh(gi[2*HID+tid] + r*ghn);
      h_s[tid] = (1.f - z)*nn + z*h_s[tid];
    }
    __syncthreads();
  }
  if (tid < 16){
    float acc = d1_b[tid];
    #pragma unroll 4
    for (int j = 0; j < HID; ++j) acc = fmaf(h_s[j], d1_w[j*16 + tid], acc);
    o1[tid] = fsilu(acc);
  }
  __syncthreads();
  if (tid < 4){
    float acc = d2_b[tid];
    #pragma unroll
    for (int j = 0; j < 16; ++j) acc = fmaf(o1[j], d2_w[j*4 + tid], acc);
    out[tid] = fsigm(fsilu(acc));
  }
}

// ---------------- launch ----------------

extern "C" void kernel_launch(void* const* d_in, const int* in_sizes, int n_in,
                              void* d_out, int out_size, void* d_ws, size_t ws_size,
                              hipStream_t stream){
  const float* features = (const float*)d_in[0];
  const int*   src      = (const int*)  d_in[1];
  const int*   dst      = (const int*)  d_in[2];
  const float* W1       = (const float*)d_in[3];
  const float* b1       = (const float*)d_in[4];
  const float* W2       = (const float*)d_in[5];
  const float* b2       = (const float*)d_in[6];
  const float* gate_w   = (const float*)d_in[7];
  const float* gate_b   = (const float*)d_in[8];
  const float* W_ih     = (const float*)d_in[9];
  const float* W_hh     = (const float*)d_in[10];
  const float* b_ih     = (const float*)d_in[11];
  const float* b_hh     = (const float*)d_in[12];
  const float* d1_w     = (const float*)d_in[13];
  const float* d1_b     = (const float*)d_in[14];
  const float* d2_w     = (const float*)d_in[15];
  const float* d2_b     = (const float*)d_in[16];
  float* out = (float*)d_out;

  const int N = NNODES, E = NEDGES, T = T_FRAMES;

  char* base = (char*)d_ws;
  size_t off = 0;
  auto alloc = [&](size_t bytes)->void*{
    void* p = base + off;
    off = (off + bytes + 255) & ~(size_t)255;
    return p;
  };
  // zero-init group (one memset): cnt_out | cnt_in | pooled
  int*    cnt_out = (int*)   alloc((size_t)N*4);
  int*    cnt_in  = (int*)   alloc((size_t)N*4);
  float*  pooled  = (float*) alloc((size_t)T*HID*4);
  size_t zero_span = off;
  int*    row_ptr = (int*)   alloc((size_t)(N+1)*4);
  int*    cursor  = (int*)   alloc((size_t)N*4);
  float*  norm_o  = (float*) alloc((size_t)N*4);
  float*  norm_i  = (float*) alloc((size_t)N*4);
  int*    es      = (int*)   alloc((size_t)E*4);
  float*  fnT     = (float*) alloc((size_t)N*T*4);
  ushort* h1s     = (ushort*)alloc((size_t)N*T*32*2);
  ushort* x2      = (ushort*)alloc((size_t)N*T*32*2);
  float*  gates   = (float*) alloc((size_t)T*N*4);
  float*  Zp      = (float*) alloc((size_t)T*GXL*4);
  float*  gi_all  = (float*) alloc((size_t)T*3*HID*4);
  ushort* W2F     = (ushort*)alloc((size_t)8*64*8*2);
  (void)ws_size; (void)in_sizes; (void)n_in; (void)out_size;

  hipMemsetAsync(d_ws, 0, zero_span, stream);

  k_degree<<<(E+255)/256, 256, 0, stream>>>(src, dst, cnt_out, cnt_in, E);
  k_scan  <<<1, 1024, 0, stream>>>(cnt_in, cnt_out, row_ptr, cursor, norm_o, norm_i, N);
  k_fill  <<<(E+255)/256, 256, 0, stream>>>(src, dst, cursor, es, E);

  k_fnT      <<<(N+63)/64, 256, 0, stream>>>(features, norm_o, fnT, N);
  k_gconv1_nm<<<N/4, 256, 0, stream>>>(fnT, row_ptr, es, norm_i, norm_o, W1, b1, h1s, N);
  k_gconv2_nm<<<N/4, 256, 0, stream>>>(h1s, row_ptr, es, norm_i, x2, N);

  k_w2frag<<<16, 256, 0, stream>>>(W2, W2F);

  k_linear_mfma<0><<<dim3(GXL, T), 256, 0, stream>>>(x2, W2F, b2, gate_w, gate_b, gates, Zp, pooled, N);
  k_linear_mfma<1><<<dim3(GXL, T), 256, 0, stream>>>(x2, W2F, b2, gate_w, gate_b, gates, Zp, pooled, N);

  k_gi <<<T, 384, 0, stream>>>(pooled, W_ih, b_ih, gi_all);
  k_gru<<<1, 768, 0, stream>>>(gi_all, W_hh, b_hh, d1_w, d1_b, d2_w, d2_b, out);
}

// Round 9
// 194.495 us; speedup vs baseline: 2.1159x; 1.1343x over previous
//
#include <hip/hip_runtime.h>
#include <stdint.h>

#define T_FRAMES 32
#define NNODES 10000
#define NEDGES 160000
#define HID 128
#define GXL 157   // ceil(625 tiles / 4 waves)

typedef short v8s __attribute__((ext_vector_type(8)));
typedef float v4f __attribute__((ext_vector_type(4)));

static __device__ __forceinline__ ushort f2bf(float f){
  uint32_t u = __float_as_uint(f);
  u += 0x7FFFu + ((u >> 16) & 1u);
  return (ushort)(u >> 16);
}
static __device__ __forceinline__ float bf_lo(uint32_t u){
  return __uint_as_float(u << 16);
}
static __device__ __forceinline__ float bf_hi(uint32_t u){
  return __uint_as_float(u & 0xffff0000u);
}
// fast native transcendentals (v_exp_f32 + v_rcp_f32)
static __device__ __forceinline__ float fsigm(float x){
  return __fdividef(1.0f, 1.0f + __expf(-x));
}
static __device__ __forceinline__ float fsilu(float x){
  return x * fsigm(x);
}
static __device__ __forceinline__ float ftanh(float x){
  return 2.0f * fsigm(2.0f * x) - 1.0f;
}

// ---------------- degree / CSR build ----------------

__global__ void k_degree(const int* __restrict__ src, const int* __restrict__ dst,
                         int* cnt_out, int* cnt_in, int E){
  int e = blockIdx.x*blockDim.x + threadIdx.x;
  if (e < E){
    atomicAdd(&cnt_out[src[e]], 1);
    atomicAdd(&cnt_in[dst[e]], 1);
  }
}

// scan over in-degrees + norms (fused), wave-shfl based
__global__ void __launch_bounds__(1024) k_scan(const int* __restrict__ cnt_in,
                                               const int* __restrict__ cnt_out,
                                               int* row_ptr, int* cursor,
                                               float* norm_out, float* norm_in, int N){
  __shared__ int wsum[16];
  __shared__ int carry_s, total_s;
  int tid = threadIdx.x;
  int lane = tid & 63, wid = tid >> 6;
  if (tid == 0) carry_s = 0;
  __syncthreads();
  for (int base = 0; base < N; base += 1024){
    int i = base + tid;
    int v = (i < N) ? cnt_in[i] : 0;
    if (i < N){
      norm_in[i]  = rsqrtf((float)max(v, 1));
      norm_out[i] = rsqrtf((float)max(cnt_out[i], 1));
    }
    int x = v;
    #pragma unroll
    for (int off = 1; off < 64; off <<= 1){
      int y = __shfl_up(x, off);
      if (lane >= off) x += y;
    }
    if (lane == 63) wsum[wid] = x;
    __syncthreads();
    if (tid == 0){
      int run = 0;
      #pragma unroll
      for (int w = 0; w < 16; ++w){ int tv = wsum[w]; wsum[w] = run; run += tv; }
      total_s = run;
    }
    __syncthreads();
    int excl = carry_s + wsum[wid] + x - v;
    if (i < N){ row_ptr[i] = excl; cursor[i] = excl; }
    __syncthreads();
    if (tid == 0) carry_s += total_s;
  }
  __syncthreads();
  if (tid == 0) row_ptr[N] = carry_s;
}

__global__ void k_fill(const int* __restrict__ src, const int* __restrict__ dst,
                       int* cursor, int* es, int E){
  int e = blockIdx.x*blockDim.x + threadIdx.x;
  if (e < E){
    int p = atomicAdd(&cursor[dst[e]], 1);
    es[p] = src[e];
  }
}

// ---------------- transpose features -> node-major, pre-scaled by norm_out ----------------

__global__ void __launch_bounds__(256) k_fnT(const float* __restrict__ feat,
                                             const float* __restrict__ norm_o,
                                             float* __restrict__ fnT, int N){
  __shared__ float sm[32][65];
  int n0 = blockIdx.x*64;
  int tid = threadIdx.x;
  for (int idx = tid; idx < 2048; idx += 256){
    int t = idx >> 6, i = idx & 63;
    int n = n0 + i;
    sm[t][i] = (n < N) ? feat[(size_t)t*N + n] : 0.f;
  }
  __syncthreads();
  for (int idx = tid; idx < 2048; idx += 256){
    int i = idx >> 5, t = idx & 31;
    int n = n0 + i;
    if (n < N) fnT[(size_t)n*32 + t] = sm[t][i] * norm_o[n];
  }
}

// ---------------- gconv1 (node-major): one wave per node ----------------

__global__ void __launch_bounds__(256) k_gconv1_nm(
    const float* __restrict__ fnT, const int* __restrict__ row_ptr,
    const int* __restrict__ es, const float* __restrict__ norm_in,
    const float* __restrict__ norm_out,
    const float* __restrict__ W1, const float* __restrict__ b1,
    ushort* __restrict__ h1s, int N){
  __shared__ float w1s[32], b1s[32];
  int tid = threadIdx.x;
  if (tid < 32){ w1s[tid] = W1[tid]; b1s[tid] = b1[tid]; }
  __syncthreads();
  int n = blockIdx.x*4 + (tid >> 6);          // N % 4 == 0
  int lane = tid & 63;
  int ep = lane >> 5, t = lane & 31;
  int s = row_ptr[n], d = row_ptr[n+1];
  float acc = 0.f;
  int e = s + ep;
  for (; e + 6 < d; e += 8){
    float v0 = fnT[(size_t)es[e]  *32 + t];
    float v1 = fnT[(size_t)es[e+2]*32 + t];
    float v2 = fnT[(size_t)es[e+4]*32 + t];
    float v3 = fnT[(size_t)es[e+6]*32 + t];
    acc += v0 + v1 + v2 + v3;
  }
  for (; e < d; e += 2)
    acc += fnT[(size_t)es[e]*32 + t];
  acc += __shfl_xor(acc, 32);
  float x1 = acc * norm_in[n];
  float x1p = __shfl(x1, lane >> 1);          // lane l gets x1[t = l>>1]
  float no = norm_out[n];
  int j0 = (lane & 1) * 16;
  uint w[8];
  #pragma unroll
  for (int q = 0; q < 8; ++q){
    float h0 = fsilu(fmaf(x1p, w1s[j0+2*q],   b1s[j0+2*q]))   * no;
    float h1 = fsilu(fmaf(x1p, w1s[j0+2*q+1], b1s[j0+2*q+1])) * no;
    w[q] = (uint)f2bf(h0) | ((uint)f2bf(h1) << 16);
  }
  uint4* dp = (uint4*)(h1s + (size_t)n*1024 + lane*16);
  dp[0] = make_uint4(w[0], w[1], w[2], w[3]);
  dp[1] = make_uint4(w[4], w[5], w[6], w[7]);
}

// ---------------- gconv2 (node-major): one wave per node, 4-edge unroll ----------------

__global__ void __launch_bounds__(256) k_gconv2_nm(
    const ushort* __restrict__ h1s, const int* __restrict__ row_ptr,
    const int* __restrict__ es, const float* __restrict__ norm_in,
    ushort* __restrict__ x2, int N){
  int tid = threadIdx.x;
  int n = blockIdx.x*4 + (tid >> 6);
  int lane = tid & 63;
  int s = row_ptr[n], d = row_ptr[n+1];
  float acc[16];
  #pragma unroll
  for (int i = 0; i < 16; ++i) acc[i] = 0.f;

  #define ACC_U4(v, base) do { \
    acc[(base)+0] += bf_lo((v).x); acc[(base)+1] += bf_hi((v).x); \
    acc[(base)+2] += bf_lo((v).y); acc[(base)+3] += bf_hi((v).y); \
    acc[(base)+4] += bf_lo((v).z); acc[(base)+5] += bf_hi((v).z); \
    acc[(base)+6] += bf_lo((v).w); acc[(base)+7] += bf_hi((v).w); \
  } while(0)

  int e = s;
  for (; e + 3 < d; e += 4){
    const uint4* p0 = (const uint4*)(h1s + (size_t)es[e]  *1024) + lane*2;
    const uint4* p1 = (const uint4*)(h1s + (size_t)es[e+1]*1024) + lane*2;
    const uint4* p2 = (const uint4*)(h1s + (size_t)es[e+2]*1024) + lane*2;
    const uint4* p3 = (const uint4*)(h1s + (size_t)es[e+3]*1024) + lane*2;
    uint4 a0 = p0[0], a1 = p0[1];
    uint4 b0 = p1[0], b1 = p1[1];
    uint4 c0 = p2[0], c1 = p2[1];
    uint4 d0 = p3[0], d1 = p3[1];
    ACC_U4(a0, 0); ACC_U4(a1, 8);
    ACC_U4(b0, 0); ACC_U4(b1, 8);
    ACC_U4(c0, 0); ACC_U4(c1, 8);
    ACC_U4(d0, 0); ACC_U4(d1, 8);
  }
  for (; e < d; ++e){
    const uint4* p0 = (const uint4*)(h1s + (size_t)es[e]*1024) + lane*2;
    uint4 a0 = p0[0], a1 = p0[1];
    ACC_U4(a0, 0); ACC_U4(a1, 8);
  }
  #undef ACC_U4

  float ni = norm_in[n];
  uint w[8];
  #pragma unroll
  for (int q = 0; q < 8; ++q)
    w[q] = (uint)f2bf(acc[2*q]*ni) | ((uint)f2bf(acc[2*q+1]*ni) << 16);
  uint4* dp = (uint4*)(x2 + (size_t)n*1024 + lane*16);
  dp[0] = make_uint4(w[0], w[1], w[2], w[3]);
  dp[1] = make_uint4(w[4], w[5], w[6], w[7]);
}

// ---------------- W2 -> bf16 MFMA B-fragments ----------------

__global__ void k_w2frag(const float* __restrict__ W2, ushort* __restrict__ W2F){
  int tid = blockIdx.x*blockDim.x + threadIdx.x;  // 0..4095
  int j = tid & 7, l = (tid >> 3) & 63, i = tid >> 9;
  int g = l >> 4, n = l & 15;
  W2F[tid] = f2bf(W2[(g*8 + j)*128 + i*16 + n]);
}

// ---------------- fused linear 32->128 + silu + gate + unnormalized pool (MFMA) --------
// h = silu(x2@W2 + b2); g_n = h_n . gate_w + gate_b
// pooled_un[t][:] += sum_n exp(g_n) * h_n ;  Zp[t][bx] = block sum exp(g_n)
// (normalization by Z happens in k_gi)

__global__ void __launch_bounds__(256) k_linear_fused(
    const ushort* __restrict__ x2, const ushort* __restrict__ W2F,
    const float* __restrict__ b2, const float* __restrict__ gate_w,
    const float* __restrict__ gate_b,
    float* __restrict__ Zp, float* __restrict__ pooled_un, int N){
  __shared__ float pool_s[128];
  __shared__ float z_s[4];
  int t = blockIdx.y;
  int tid = threadIdx.x;
  int wave = tid >> 6, lane = tid & 63;
  int g = lane >> 4, n = lane & 15;
  if (tid < 128) pool_s[tid] = 0.f;
  if (tid < 4) z_s[tid] = 0.f;
  __syncthreads();
  int tile = blockIdx.x*4 + wave;          // 16-node tile; N = 625*16
  bool active = (tile*16 < N);

  const v8s* W2Fv = (const v8s*)W2F;
  v8s bfrag[8];
  #pragma unroll
  for (int i = 0; i < 8; ++i) bfrag[i] = W2Fv[i*64 + lane];
  v4f acc[8];
  #pragma unroll
  for (int i = 0; i < 8; ++i){
    float bv = b2[i*16 + n];
    acc[i] = (v4f){bv, bv, bv, bv};
  }
  if (active){
    int nb = tile*16;
    const v8s* ap = (const v8s*)(x2 + (size_t)(nb + (lane & 15))*1024 + t*32);
    v8s a = ap[g];
    #pragma unroll
    for (int i = 0; i < 8; ++i)
      acc[i] = __builtin_amdgcn_mfma_f32_16x16x32_bf16(a, bfrag[i], acc[i], 0, 0, 0);

    // C/D layout: value (i,r) = h[node nb + g*4 + r][col i*16 + n]
    float gw8[8];
    #pragma unroll
    for (int i = 0; i < 8; ++i) gw8[i] = gate_w[i*16 + n];
    float gp[4] = {0.f, 0.f, 0.f, 0.f};
    #pragma unroll
    for (int i = 0; i < 8; ++i){
      #pragma unroll
      for (int r = 0; r < 4; ++r) gp[r] += fsilu(acc[i][r]) * gw8[i];
    }
    // butterfly over the 16 n-lanes: all lanes get the full gate for node g*4+r
    #pragma unroll
    for (int m = 1; m < 16; m <<= 1){
      #pragma unroll
      for (int r = 0; r < 4; ++r) gp[r] += __shfl_xor(gp[r], m);
    }
    float gb = gate_b[0];
    float wn[4];
    #pragma unroll
    for (int r = 0; r < 4; ++r) wn[r] = __expf(gp[r] + gb);

    // Z partial: one lane per group contributes sum_r wn[r]
    float se = (n == 0) ? (wn[0] + wn[1] + wn[2] + wn[3]) : 0.f;
    se += __shfl_xor(se, 16);
    se += __shfl_xor(se, 32);
    if (lane == 0) z_s[wave] = se;

    // weighted pool: cs[i] = sum over this wave's 16 nodes of exp(g)*h
    float cs[8];
    #pragma unroll
    for (int i = 0; i < 8; ++i){
      float c = 0.f;
      #pragma unroll
      for (int r = 0; r < 4; ++r) c += fsilu(acc[i][r]) * wn[r];
      c += __shfl_xor(c, 16);
      c += __shfl_xor(c, 32);
      cs[i] = c;
    }
    if (lane < 16){
      #pragma unroll
      for (int i = 0; i < 8; ++i) atomicAdd(&pool_s[i*16 + lane], cs[i]);
    }
  }
  __syncthreads();
  if (tid == 0)
    Zp[(size_t)t*GXL + blockIdx.x] = z_s[0] + z_s[1] + z_s[2] + z_s[3];
  if (tid < 128) atomicAdd(&pooled_un[(size_t)t*HID + tid], pool_s[tid]);
}

// ---------------- GRU + head ----------------
// normalizes pooled_un by Z (reduced from Zp) then gi = pooled . W_ih^T + b_ih

__global__ void __launch_bounds__(384) k_gi(const float* __restrict__ pooled_un,
                                            const float* __restrict__ Zp,
                                            const float* __restrict__ W_ih,
                                            const float* __restrict__ b_ih,
                                            float* __restrict__ gi_all){
  __shared__ float ps[HID];
  __shared__ float zred[6];
  int t = blockIdx.x, tid = threadIdx.x;   // 384 threads
  int lane = tid & 63, wid = tid >> 6;
  // reduce Zp row (157 values) across the block
  float zs = 0.f;
  for (int i = tid; i < GXL; i += 384) zs += Zp[(size_t)t*GXL + i];
  #pragma unroll
  for (int m = 32; m; m >>= 1) zs += __shfl_xor(zs, m);
  if (lane == 0) zred[wid] = zs;
  __syncthreads();
  float invZ = __fdividef(1.0f, zred[0]+zred[1]+zred[2]+zred[3]+zred[4]+zred[5]);
  if (tid < HID) ps[tid] = pooled_un[(size_t)t*HID + tid] * invZ;
  __syncthreads();
  float acc = b_ih[tid];
  const float4* wr = (const float4*)(W_ih + (size_t)tid*HID);
  const float4* p4 = (const float4*)ps;
  #pragma unroll
  for (int q = 0; q < HID/4; ++q){
    float4 wv = wr[q], pv = p4[q];
    acc = fmaf(wv.x, pv.x, acc);
    acc = fmaf(wv.y, pv.y, acc);
    acc = fmaf(wv.z, pv.z, acc);
    acc = fmaf(wv.w, pv.w, acc);
  }
  gi_all[t*384 + tid] = acc;
}

// split-K GRU: 768 threads, each owns 64 weight floats (16 float4) in registers.
__global__ void __launch_bounds__(768) k_gru(
    const float* __restrict__ gi_all, const float* __restrict__ W_hh,
    const float* __restrict__ b_hh,
    const float* __restrict__ d1_w, const float* __restrict__ d1_b,
    const float* __restrict__ d2_w, const float* __restrict__ d2_b,
    float* __restrict__ out){
  __shared__ float gi_s[T_FRAMES*3*HID];   // 48 KB
  __shared__ float ps[2*384];              // split-K partials
  __shared__ float h_s[HID];
  __shared__ float o1[16];
  int tid = threadIdx.x;  // 768
  int half = (tid >= 384) ? 1 : 0;
  int o = tid - half*384;

  for (int i = tid; i < T_FRAMES*3*HID; i += 768) gi_s[i] = gi_all[i];

  const float4* wr = (const float4*)(W_hh + (size_t)o*HID + half*64);  // 16 vec4
  #define LDW(i) float4 W##i = wr[i];
  LDW(0) LDW(1) LDW(2) LDW(3) LDW(4) LDW(5) LDW(6) LDW(7)
  LDW(8) LDW(9) LDW(10) LDW(11) LDW(12) LDW(13) LDW(14) LDW(15)
  #undef LDW
  float bh2 = half ? 0.f : b_hh[o];

  if (tid < HID) h_s[tid] = 0.f;
  __syncthreads();

  for (int t = 0; t < T_FRAMES; ++t){
    const float4* p4 = (const float4*)h_s + half*16;
    float acc = bh2;
    #define STEP(i) { float4 pv = p4[i]; \
      acc = fmaf(W##i.x, pv.x, acc); acc = fmaf(W##i.y, pv.y, acc); \
      acc = fmaf(W##i.z, pv.z, acc); acc = fmaf(W##i.w, pv.w, acc); }
    STEP(0) STEP(1) STEP(2) STEP(3) STEP(4) STEP(5) STEP(6) STEP(7)
    STEP(8) STEP(9) STEP(10) STEP(11) STEP(12) STEP(13) STEP(14) STEP(15)
    #undef STEP
    ps[tid] = acc;
    __syncthreads();
    if (tid < HID){
      const float* gi = gi_s + t*384;
      float ghr = ps[tid]       + ps[384+tid];
      float ghz = ps[128+tid]   + ps[512+tid];
      float ghn = ps[256+tid]   + ps[640+tid];
      float r  = fsigm(gi[tid]       + ghr);
      float z  = fsigm(gi[HID+tid]   + ghz);
      float nn = ftanh(gi[2*HID+tid] + r*ghn);
      h_s[tid] = (1.f - z)*nn + z*h_s[tid];
    }
    __syncthreads();
  }
  if (tid < 16){
    float acc = d1_b[tid];
    #pragma unroll 4
    for (int j = 0; j < HID; ++j) acc = fmaf(h_s[j], d1_w[j*16 + tid], acc);
    o1[tid] = fsilu(acc);
  }
  __syncthreads();
  if (tid < 4){
    float acc = d2_b[tid];
    #pragma unroll
    for (int j = 0; j < 16; ++j) acc = fmaf(o1[j], d2_w[j*4 + tid], acc);
    out[tid] = fsigm(fsilu(acc));
  }
}

// ---------------- launch ----------------

extern "C" void kernel_launch(void* const* d_in, const int* in_sizes, int n_in,
                              void* d_out, int out_size, void* d_ws, size_t ws_size,
                              hipStream_t stream){
  const float* features = (const float*)d_in[0];
  const int*   src      = (const int*)  d_in[1];
  const int*   dst      = (const int*)  d_in[2];
  const float* W1       = (const float*)d_in[3];
  const float* b1       = (const float*)d_in[4];
  const float* W2       = (const float*)d_in[5];
  const float* b2       = (const float*)d_in[6];
  const float* gate_w   = (const float*)d_in[7];
  const float* gate_b   = (const float*)d_in[8];
  const float* W_ih     = (const float*)d_in[9];
  const float* W_hh     = (const float*)d_in[10];
  const float* b_ih     = (const float*)d_in[11];
  const float* b_hh     = (const float*)d_in[12];
  const float* d1_w     = (const float*)d_in[13];
  const float* d1_b     = (const float*)d_in[14];
  const float* d2_w     = (const float*)d_in[15];
  const float* d2_b     = (const float*)d_in[16];
  float* out = (float*)d_out;

  const int N = NNODES, E = NEDGES, T = T_FRAMES;

  char* base = (char*)d_ws;
  size_t off = 0;
  auto alloc = [&](size_t bytes)->void*{
    void* p = base + off;
    off = (off + bytes + 255) & ~(size_t)255;
    return p;
  };
  // zero-init group (one memset): cnt_out | cnt_in | pooled_un
  int*    cnt_out = (int*)   alloc((size_t)N*4);
  int*    cnt_in  = (int*)   alloc((size_t)N*4);
  float*  pooled  = (float*) alloc((size_t)T*HID*4);
  size_t zero_span = off;
  int*    row_ptr = (int*)   alloc((size_t)(N+1)*4);
  int*    cursor  = (int*)   alloc((size_t)N*4);
  float*  norm_o  = (float*) alloc((size_t)N*4);
  float*  norm_i  = (float*) alloc((size_t)N*4);
  int*    es      = (int*)   alloc((size_t)E*4);
  float*  fnT     = (float*) alloc((size_t)N*T*4);
  ushort* h1s     = (ushort*)alloc((size_t)N*T*32*2);
  ushort* x2      = (ushort*)alloc((size_t)N*T*32*2);
  float*  Zp      = (float*) alloc((size_t)T*GXL*4);
  float*  gi_all  = (float*) alloc((size_t)T*3*HID*4);
  ushort* W2F     = (ushort*)alloc((size_t)8*64*8*2);
  (void)ws_size; (void)in_sizes; (void)n_in; (void)out_size;

  hipMemsetAsync(d_ws, 0, zero_span, stream);

  k_degree<<<(E+255)/256, 256, 0, stream>>>(src, dst, cnt_out, cnt_in, E);
  k_scan  <<<1, 1024, 0, stream>>>(cnt_in, cnt_out, row_ptr, cursor, norm_o, norm_i, N);
  k_fill  <<<(E+255)/256, 256, 0, stream>>>(src, dst, cursor, es, E);

  k_fnT      <<<(N+63)/64, 256, 0, stream>>>(features, norm_o, fnT, N);
  k_gconv1_nm<<<N/4, 256, 0, stream>>>(fnT, row_ptr, es, norm_i, norm_o, W1, b1, h1s, N);
  k_gconv2_nm<<<N/4, 256, 0, stream>>>(h1s, row_ptr, es, norm_i, x2, N);

  k_w2frag<<<16, 256, 0, stream>>>(W2, W2F);

  k_linear_fused<<<dim3(GXL, T), 256, 0, stream>>>(x2, W2F, b2, gate_w, gate_b, Zp, pooled, N);

  k_gi <<<T, 384, 0, stream>>>(pooled, Zp, W_ih, b_ih, gi_all);
  k_gru<<<1, 768, 0, stream>>>(gi_all, W_hh, b_hh, d1_w, d1_b, d2_w, d2_b, out);
}

// Round 10
// 175.452 us; speedup vs baseline: 2.3455x; 1.1085x over previous
//
#include <hip/hip_runtime.h>
#include <stdint.h>

#define T_FRAMES 32
#define NNODES 10000
#define NEDGES 160000
#define HID 128
#define GXL 157   // ceil(625 tiles / 4 waves)

// int8 quantization of h1: u = round(h*512) + 128, clamp [0,255]; |h1| < 0.21 so no saturation
#define H1_SCALE 512.0f
#define H1_INV   (1.0f/512.0f)

typedef short v8s __attribute__((ext_vector_type(8)));
typedef float v4f __attribute__((ext_vector_type(4)));

static __device__ __forceinline__ ushort f2bf(float f){
  uint32_t u = __float_as_uint(f);
  u += 0x7FFFu + ((u >> 16) & 1u);
  return (ushort)(u >> 16);
}
// fast native transcendentals (v_exp_f32 + v_rcp_f32)
static __device__ __forceinline__ float fsigm(float x){
  return __fdividef(1.0f, 1.0f + __expf(-x));
}
static __device__ __forceinline__ float fsilu(float x){
  return x * fsigm(x);
}
static __device__ __forceinline__ float ftanh(float x){
  return 2.0f * fsigm(2.0f * x) - 1.0f;
}

// ---------------- degree / CSR build ----------------

__global__ void k_degree(const int* __restrict__ src, const int* __restrict__ dst,
                         int* cnt_out, int* cnt_in, int E){
  int e = blockIdx.x*blockDim.x + threadIdx.x;
  if (e < E){
    atomicAdd(&cnt_out[src[e]], 1);
    atomicAdd(&cnt_in[dst[e]], 1);
  }
}

// scan over in-degrees + norms (fused), wave-shfl based
__global__ void __launch_bounds__(1024) k_scan(const int* __restrict__ cnt_in,
                                               const int* __restrict__ cnt_out,
                                               int* row_ptr, int* cursor,
                                               float* norm_out, float* norm_in, int N){
  __shared__ int wsum[16];
  __shared__ int carry_s, total_s;
  int tid = threadIdx.x;
  int lane = tid & 63, wid = tid >> 6;
  if (tid == 0) carry_s = 0;
  __syncthreads();
  for (int base = 0; base < N; base += 1024){
    int i = base + tid;
    int v = (i < N) ? cnt_in[i] : 0;
    if (i < N){
      norm_in[i]  = rsqrtf((float)max(v, 1));
      norm_out[i] = rsqrtf((float)max(cnt_out[i], 1));
    }
    int x = v;
    #pragma unroll
    for (int off = 1; off < 64; off <<= 1){
      int y = __shfl_up(x, off);
      if (lane >= off) x += y;
    }
    if (lane == 63) wsum[wid] = x;
    __syncthreads();
    if (tid == 0){
      int run = 0;
      #pragma unroll
      for (int w = 0; w < 16; ++w){ int tv = wsum[w]; wsum[w] = run; run += tv; }
      total_s = run;
    }
    __syncthreads();
    int excl = carry_s + wsum[wid] + x - v;
    if (i < N){ row_ptr[i] = excl; cursor[i] = excl; }
    __syncthreads();
    if (tid == 0) carry_s += total_s;
  }
  __syncthreads();
  if (tid == 0) row_ptr[N] = carry_s;
}

__global__ void k_fill(const int* __restrict__ src, const int* __restrict__ dst,
                       int* cursor, int* es, int E){
  int e = blockIdx.x*blockDim.x + threadIdx.x;
  if (e < E){
    int p = atomicAdd(&cursor[dst[e]], 1);
    es[p] = src[e];
  }
}

// ---------------- transpose features -> node-major, pre-scaled by norm_out ----------------

__global__ void __launch_bounds__(256) k_fnT(const float* __restrict__ feat,
                                             const float* __restrict__ norm_o,
                                             float* __restrict__ fnT, int N){
  __shared__ float sm[32][65];
  int n0 = blockIdx.x*64;
  int tid = threadIdx.x;
  for (int idx = tid; idx < 2048; idx += 256){
    int t = idx >> 6, i = idx & 63;
    int n = n0 + i;
    sm[t][i] = (n < N) ? feat[(size_t)t*N + n] : 0.f;
  }
  __syncthreads();
  for (int idx = tid; idx < 2048; idx += 256){
    int i = idx >> 5, t = idx & 31;
    int n = n0 + i;
    if (n < N) fnT[(size_t)n*32 + t] = sm[t][i] * norm_o[n];
  }
}

// ---------------- gconv1 (node-major): one wave per node, int8 h1 output ----------------

__global__ void __launch_bounds__(256) k_gconv1_nm(
    const float* __restrict__ fnT, const int* __restrict__ row_ptr,
    const int* __restrict__ es, const float* __restrict__ norm_in,
    const float* __restrict__ norm_out,
    const float* __restrict__ W1, const float* __restrict__ b1,
    uchar* __restrict__ h1s, int N){
  __shared__ float w1s[32], b1s[32];
  int tid = threadIdx.x;
  if (tid < 32){ w1s[tid] = W1[tid]; b1s[tid] = b1[tid]; }
  __syncthreads();
  int n = blockIdx.x*4 + (tid >> 6);          // N % 4 == 0
  int lane = tid & 63;
  int ep = lane >> 5, t = lane & 31;
  int s = row_ptr[n], d = row_ptr[n+1];
  float acc = 0.f;
  int e = s + ep;
  for (; e + 6 < d; e += 8){
    float v0 = fnT[(size_t)es[e]  *32 + t];
    float v1 = fnT[(size_t)es[e+2]*32 + t];
    float v2 = fnT[(size_t)es[e+4]*32 + t];
    float v3 = fnT[(size_t)es[e+6]*32 + t];
    acc += v0 + v1 + v2 + v3;
  }
  for (; e < d; e += 2)
    acc += fnT[(size_t)es[e]*32 + t];
  acc += __shfl_xor(acc, 32);
  float x1 = acc * norm_in[n];
  float x1p = __shfl(x1, lane >> 1);          // lane l gets x1[t = l>>1]
  float no = norm_out[n];
  int j0 = (lane & 1) * 16;
  float hv[16];
  #pragma unroll
  for (int q = 0; q < 16; ++q)
    hv[q] = fsilu(fmaf(x1p, w1s[j0+q], b1s[j0+q])) * no;
  uint b[4] = {0u, 0u, 0u, 0u};
  #pragma unroll
  for (int q = 0; q < 16; ++q){
    float t8 = fminf(fmaxf(fmaf(hv[q], H1_SCALE, 128.5f), 0.f), 255.f);
    b[q >> 2] |= ((uint)(int)t8) << ((q & 3) * 8);
  }
  *(uint4*)(h1s + (size_t)n*1024 + lane*16) = make_uint4(b[0], b[1], b[2], b[3]);
}

// ---------------- gconv2 (node-major): one wave per node, int8 gather, 8-edge unroll ----
// x2[n][t][j] = norm_in[n] * sum_e h1[es[e]][t][j];  h1 byte u -> (u-128)/512

__global__ void __launch_bounds__(256) k_gconv2_nm(
    const uchar* __restrict__ h1s, const int* __restrict__ row_ptr,
    const int* __restrict__ es, const float* __restrict__ norm_in,
    ushort* __restrict__ x2, int N){
  int tid = threadIdx.x;
  int n = blockIdx.x*4 + (tid >> 6);
  int lane = tid & 63;
  int s = row_ptr[n], d = row_ptr[n+1];
  float acc[16];
  #pragma unroll
  for (int i = 0; i < 16; ++i) acc[i] = 0.f;

  // byte k of uint4 -> acc[k]; uitofp of (and/lshr) pattern-matches v_cvt_f32_ubyteN
  #define ACCB(v) do { \
    acc[0]  += (float)((v).x & 0xffu);         acc[1]  += (float)(((v).x >> 8) & 0xffu); \
    acc[2]  += (float)(((v).x >> 16) & 0xffu); acc[3]  += (float)((v).x >> 24); \
    acc[4]  += (float)((v).y & 0xffu);         acc[5]  += (float)(((v).y >> 8) & 0xffu); \
    acc[6]  += (float)(((v).y >> 16) & 0xffu); acc[7]  += (float)((v).y >> 24); \
    acc[8]  += (float)((v).z & 0xffu);         acc[9]  += (float)(((v).z >> 8) & 0xffu); \
    acc[10] += (float)(((v).z >> 16) & 0xffu); acc[11] += (float)((v).z >> 24); \
    acc[12] += (float)((v).w & 0xffu);         acc[13] += (float)(((v).w >> 8) & 0xffu); \
    acc[14] += (float)(((v).w >> 16) & 0xffu); acc[15] += (float)((v).w >> 24); \
  } while(0)

  int e = s;
  for (; e + 7 < d; e += 8){
    const uint4* q0 = (const uint4*)(h1s + (size_t)es[e]  *1024) + lane;
    const uint4* q1 = (const uint4*)(h1s + (size_t)es[e+1]*1024) + lane;
    const uint4* q2 = (const uint4*)(h1s + (size_t)es[e+2]*1024) + lane;
    const uint4* q3 = (const uint4*)(h1s + (size_t)es[e+3]*1024) + lane;
    const uint4* q4 = (const uint4*)(h1s + (size_t)es[e+4]*1024) + lane;
    const uint4* q5 = (const uint4*)(h1s + (size_t)es[e+5]*1024) + lane;
    const uint4* q6 = (const uint4*)(h1s + (size_t)es[e+6]*1024) + lane;
    const uint4* q7 = (const uint4*)(h1s + (size_t)es[e+7]*1024) + lane;
    uint4 w0 = *q0, w1 = *q1, w2 = *q2, w3 = *q3;
    uint4 w4 = *q4, w5 = *q5, w6 = *q6, w7 = *q7;
    ACCB(w0); ACCB(w1); ACCB(w2); ACCB(w3);
    ACCB(w4); ACCB(w5); ACCB(w6); ACCB(w7);
  }
  for (; e < d; ++e){
    uint4 w0 = *((const uint4*)(h1s + (size_t)es[e]*1024) + lane);
    ACCB(w0);
  }
  #undef ACCB

  float ni = norm_in[n];
  float corr = -128.0f * (float)(d - s);     // remove +128 bias: sum(u) + corr = sum(u-128)
  float sc = H1_INV * ni;
  uint w[8];
  #pragma unroll
  for (int q = 0; q < 8; ++q){
    float v0 = (acc[2*q]   + corr) * sc;
    float v1 = (acc[2*q+1] + corr) * sc;
    w[q] = (uint)f2bf(v0) | ((uint)f2bf(v1) << 16);
  }
  uint4* dp = (uint4*)(x2 + (size_t)n*1024 + lane*16);
  dp[0] = make_uint4(w[0], w[1], w[2], w[3]);
  dp[1] = make_uint4(w[4], w[5], w[6], w[7]);
}

// ---------------- W2 -> bf16 MFMA B-fragments ----------------

__global__ void k_w2frag(const float* __restrict__ W2, ushort* __restrict__ W2F){
  int tid = blockIdx.x*blockDim.x + threadIdx.x;  // 0..4095
  int j = tid & 7, l = (tid >> 3) & 63, i = tid >> 9;
  int g = l >> 4, n = l & 15;
  W2F[tid] = f2bf(W2[(g*8 + j)*128 + i*16 + n]);
}

// ---------------- fused linear 32->128 + silu + gate + unnormalized pool (MFMA) --------

__global__ void __launch_bounds__(256) k_linear_fused(
    const ushort* __restrict__ x2, const ushort* __restrict__ W2F,
    const float* __restrict__ b2, const float* __restrict__ gate_w,
    const float* __restrict__ gate_b,
    float* __restrict__ Zp, float* __restrict__ pooled_un, int N){
  __shared__ float pool_s[128];
  __shared__ float z_s[4];
  int t = blockIdx.y;
  int tid = threadIdx.x;
  int wave = tid >> 6, lane = tid & 63;
  int g = lane >> 4, n = lane & 15;
  if (tid < 128) pool_s[tid] = 0.f;
  if (tid < 4) z_s[tid] = 0.f;
  __syncthreads();
  int tile = blockIdx.x*4 + wave;          // 16-node tile; N = 625*16
  bool active = (tile*16 < N);

  const v8s* W2Fv = (const v8s*)W2F;
  v8s bfrag[8];
  #pragma unroll
  for (int i = 0; i < 8; ++i) bfrag[i] = W2Fv[i*64 + lane];
  v4f acc[8];
  #pragma unroll
  for (int i = 0; i < 8; ++i){
    float bv = b2[i*16 + n];
    acc[i] = (v4f){bv, bv, bv, bv};
  }
  if (active){
    int nb = tile*16;
    const v8s* ap = (const v8s*)(x2 + (size_t)(nb + (lane & 15))*1024 + t*32);
    v8s a = ap[g];
    #pragma unroll
    for (int i = 0; i < 8; ++i)
      acc[i] = __builtin_amdgcn_mfma_f32_16x16x32_bf16(a, bfrag[i], acc[i], 0, 0, 0);

    // C/D layout: value (i,r) = h[node nb + g*4 + r][col i*16 + n]
    float gw8[8];
    #pragma unroll
    for (int i = 0; i < 8; ++i) gw8[i] = gate_w[i*16 + n];
    float gp[4] = {0.f, 0.f, 0.f, 0.f};
    #pragma unroll
    for (int i = 0; i < 8; ++i){
      #pragma unroll
      for (int r = 0; r < 4; ++r) gp[r] += fsilu(acc[i][r]) * gw8[i];
    }
    #pragma unroll
    for (int m = 1; m < 16; m <<= 1){
      #pragma unroll
      for (int r = 0; r < 4; ++r) gp[r] += __shfl_xor(gp[r], m);
    }
    float gb = gate_b[0];
    float wn[4];
    #pragma unroll
    for (int r = 0; r < 4; ++r) wn[r] = __expf(gp[r] + gb);

    float se = (n == 0) ? (wn[0] + wn[1] + wn[2] + wn[3]) : 0.f;
    se += __shfl_xor(se, 16);
    se += __shfl_xor(se, 32);
    if (lane == 0) z_s[wave] = se;

    float cs[8];
    #pragma unroll
    for (int i = 0; i < 8; ++i){
      float c = 0.f;
      #pragma unroll
      for (int r = 0; r < 4; ++r) c += fsilu(acc[i][r]) * wn[r];
      c += __shfl_xor(c, 16);
      c += __shfl_xor(c, 32);
      cs[i] = c;
    }
    if (lane < 16){
      #pragma unroll
      for (int i = 0; i < 8; ++i) atomicAdd(&pool_s[i*16 + lane], cs[i]);
    }
  }
  __syncthreads();
  if (tid == 0)
    Zp[(size_t)t*GXL + blockIdx.x] = z_s[0] + z_s[1] + z_s[2] + z_s[3];
  if (tid < 128) atomicAdd(&pooled_un[(size_t)t*HID + tid], pool_s[tid]);
}

// ---------------- GRU + head ----------------

__global__ void __launch_bounds__(384) k_gi(const float* __restrict__ pooled_un,
                                            const float* __restrict__ Zp,
                                            const float* __restrict__ W_ih,
                                            const float* __restrict__ b_ih,
                                            float* __restrict__ gi_all){
  __shared__ float ps[HID];
  __shared__ float zred[6];
  int t = blockIdx.x, tid = threadIdx.x;   // 384 threads
  int lane = tid & 63, wid = tid >> 6;
  float zs = 0.f;
  for (int i = tid; i < GXL; i += 384) zs += Zp[(size_t)t*GXL + i];
  #pragma unroll
  for (int m = 32; m; m >>= 1) zs += __shfl_xor(zs, m);
  if (lane == 0) zred[wid] = zs;
  __syncthreads();
  float invZ = __fdividef(1.0f, zred[0]+zred[1]+zred[2]+zred[3]+zred[4]+zred[5]);
  if (tid < HID) ps[tid] = pooled_un[(size_t)t*HID + tid] * invZ;
  __syncthreads();
  float acc = b_ih[tid];
  const float4* wr = (const float4*)(W_ih + (size_t)tid*HID);
  const float4* p4 = (const float4*)ps;
  #pragma unroll
  for (int q = 0; q < HID/4; ++q){
    float4 wv = wr[q], pv = p4[q];
    acc = fmaf(wv.x, pv.x, acc);
    acc = fmaf(wv.y, pv.y, acc);
    acc = fmaf(wv.z, pv.z, acc);
    acc = fmaf(wv.w, pv.w, acc);
  }
  gi_all[t*384 + tid] = acc;
}

// split-K GRU: 768 threads, each owns 64 weight floats (16 float4) in registers.
__global__ void __launch_bounds__(768) k_gru(
    const float* __restrict__ gi_all, const float* __restrict__ W_hh,
    const float* __restrict__ b_hh,
    const float* __restrict__ d1_w, const float* __restrict__ d1_b,
    const float* __restrict__ d2_w, const float* __restrict__ d2_b,
    float* __restrict__ out){
  __shared__ float gi_s[T_FRAMES*3*HID];   // 48 KB
  __shared__ float ps[2*384];              // split-K partials
  __shared__ float h_s[HID];
  __shared__ float o1[16];
  int tid = threadIdx.x;  // 768
  int half = (tid >= 384) ? 1 : 0;
  int o = tid - half*384;

  for (int i = tid; i < T_FRAMES*3*HID; i += 768) gi_s[i] = gi_all[i];

  const float4* wr = (const float4*)(W_hh + (size_t)o*HID + half*64);  // 16 vec4
  #define LDW(i) float4 W##i = wr[i];
  LDW(0) LDW(1) LDW(2) LDW(3) LDW(4) LDW(5) LDW(6) LDW(7)
  LDW(8) LDW(9) LDW(10) LDW(11) LDW(12) LDW(13) LDW(14) LDW(15)
  #undef LDW
  float bh2 = half ? 0.f : b_hh[o];

  if (tid < HID) h_s[tid] = 0.f;
  __syncthreads();

  for (int t = 0; t < T_FRAMES; ++t){
    const float4* p4 = (const float4*)h_s + half*16;
    float acc = bh2;
    #define STEP(i) { float4 pv = p4[i]; \
      acc = fmaf(W##i.x, pv.x, acc); acc = fmaf(W##i.y, pv.y, acc); \
      acc = fmaf(W##i.z, pv.z, acc); acc = fmaf(W##i.w, pv.w, acc); }
    STEP(0) STEP(1) STEP(2) STEP(3) STEP(4) STEP(5) STEP(6) STEP(7)
    STEP(8) STEP(9) STEP(10) STEP(11) STEP(12) STEP(13) STEP(14) STEP(15)
    #undef STEP
    ps[tid] = acc;
    __syncthreads();
    if (tid < HID){
      const float* gi = gi_s + t*384;
      float ghr = ps[tid]       + ps[384+tid];
      float ghz = ps[128+tid]   + ps[512+tid];
      float ghn = ps[256+tid]   + ps[640+tid];
      float r  = fsigm(gi[tid]       + ghr);
      float z  = fsigm(gi[HID+tid]   + ghz);
      float nn = ftanh(gi[2*HID+tid] + r*ghn);
      h_s[tid] = (1.f - z)*nn + z*h_s[tid];
    }
    __syncthreads();
  }
  if (tid < 16){
    float acc = d1_b[tid];
    #pragma unroll 4
    for (int j = 0; j < HID; ++j) acc = fmaf(h_s[j], d1_w[j*16 + tid], acc);
    o1[tid] = fsilu(acc);
  }
  __syncthreads();
  if (tid < 4){
    float acc = d2_b[tid];
    #pragma unroll
    for (int j = 0; j < 16; ++j) acc = fmaf(o1[j], d2_w[j*4 + tid], acc);
    out[tid] = fsigm(fsilu(acc));
  }
}

// ---------------- launch ----------------

extern "C" void kernel_launch(void* const* d_in, const int* in_sizes, int n_in,
                              void* d_out, int out_size, void* d_ws, size_t ws_size,
                              hipStream_t stream){
  const float* features = (const float*)d_in[0];
  const int*   src      = (const int*)  d_in[1];
  const int*   dst      = (const int*)  d_in[2];
  const float* W1       = (const float*)d_in[3];
  const float* b1       = (const float*)d_in[4];
  const float* W2       = (const float*)d_in[5];
  const float* b2       = (const float*)d_in[6];
  const float* gate_w   = (const float*)d_in[7];
  const float* gate_b   = (const float*)d_in[8];
  const float* W_ih     = (const float*)d_in[9];
  const float* W_hh     = (const float*)d_in[10];
  const float* b_ih     = (const float*)d_in[11];
  const float* b_hh     = (const float*)d_in[12];
  const float* d1_w     = (const float*)d_in[13];
  const float* d1_b     = (const float*)d_in[14];
  const float* d2_w     = (const float*)d_in[15];
  const float* d2_b     = (const float*)d_in[16];
  float* out = (float*)d_out;

  const int N = NNODES, E = NEDGES, T = T_FRAMES;

  char* base = (char*)d_ws;
  size_t off = 0;
  auto alloc = [&](size_t bytes)->void*{
    void* p = base + off;
    off = (off + bytes + 255) & ~(size_t)255;
    return p;
  };
  // zero-init group (one memset): cnt_out | cnt_in | pooled_un
  int*    cnt_out = (int*)   alloc((size_t)N*4);
  int*    cnt_in  = (int*)   alloc((size_t)N*4);
  float*  pooled  = (float*) alloc((size_t)T*HID*4);
  size_t zero_span = off;
  int*    row_ptr = (int*)   alloc((size_t)(N+1)*4);
  int*    cursor  = (int*)   alloc((size_t)N*4);
  float*  norm_o  = (float*) alloc((size_t)N*4);
  float*  norm_i  = (float*) alloc((size_t)N*4);
  int*    es      = (int*)   alloc((size_t)E*4);
  float*  fnT     = (float*) alloc((size_t)N*T*4);
  uchar*  h1s     = (uchar*) alloc((size_t)N*1024);
  ushort* x2      = (ushort*)alloc((size_t)N*T*32*2);
  float*  Zp      = (float*) alloc((size_t)T*GXL*4);
  float*  gi_all  = (float*) alloc((size_t)T*3*HID*4);
  ushort* W2F     = (ushort*)alloc((size_t)8*64*8*2);
  (void)ws_size; (void)in_sizes; (void)n_in; (void)out_size;

  hipMemsetAsync(d_ws, 0, zero_span, stream);

  k_degree<<<(E+255)/256, 256, 0, stream>>>(src, dst, cnt_out, cnt_in, E);
  k_scan  <<<1, 1024, 0, stream>>>(cnt_in, cnt_out, row_ptr, cursor, norm_o, norm_i, N);
  k_fill  <<<(E+255)/256, 256, 0, stream>>>(src, dst, cursor, es, E);

  k_fnT      <<<(N+63)/64, 256, 0, stream>>>(features, norm_o, fnT, N);
  k_gconv1_nm<<<N/4, 256, 0, stream>>>(fnT, row_ptr, es, norm_i, norm_o, W1, b1, h1s, N);
  k_gconv2_nm<<<N/4, 256, 0, stream>>>(h1s, row_ptr, es, norm_i, x2, N);

  k_w2frag<<<16, 256, 0, stream>>>(W2, W2F);

  k_linear_fused<<<dim3(GXL, T), 256, 0, stream>>>(x2, W2F, b2, gate_w, gate_b, Zp, pooled, N);

  k_gi <<<T, 384, 0, stream>>>(pooled, Zp, W_ih, b_ih, gi_all);
  k_gru<<<1, 768, 0, stream>>>(gi_all, W_hh, b_hh, d1_w, d1_b, d2_w, d2_b, out);
}